// Round 1
// baseline (1273.800 us; speedup 1.0000x reference)
//
#include <hip/hip_runtime.h>
#include <math.h>

#define EPSF 1e-7f

__device__ __forceinline__ float arcosh_f(float x) {
    x = fmaxf(x, 1.0f + EPSF);
    return logf(x + sqrtf(x * x - 1.0f));
}

// power-of-two blockDim reduce; sbuf has blockDim floats; result broadcast to all
__device__ __forceinline__ float blockReduceSumF(float v, float* sbuf) {
    int tid = threadIdx.x;
    sbuf[tid] = v;
    __syncthreads();
    for (int st = blockDim.x >> 1; st > 0; st >>= 1) {
        if (tid < st) sbuf[tid] += sbuf[tid + st];
        __syncthreads();
    }
    float r = sbuf[0];
    __syncthreads();
    return r;
}

// ---------- K1: xt0 = log_map_zero(x), elem0 = 0. block = 128 thr, 1 node ----------
__global__ __launch_bounds__(128) void k_log0(const float* __restrict__ x,
                                              float* __restrict__ xt0, int N) {
    int i = blockIdx.x;
    int t = threadIdx.x;
    __shared__ float sred[128];
    __shared__ float sy0;
    float v = x[(size_t)i * 128 + t];
    if (t == 0) sy0 = v;
    float s = blockReduceSumF((t >= 1) ? v * v : 0.f, sred);  // has syncthreads -> sy0 visible
    float y0 = sy0;
    float dist = arcosh_f(y0 + EPSF);
    float nrm = sqrtf(s + EPSF);
    float scl = dist / nrm;
    xt0[(size_t)i * 128 + t] = (t == 0) ? 0.f : scl * v;
}

// ---------- CSR build ----------
__global__ void k_zero_i(int* __restrict__ p, int n) {
    int i = blockIdx.x * blockDim.x + threadIdx.x;
    if (i < n) p[i] = 0;
}
__global__ void k_copy_i(const int* __restrict__ a, int* __restrict__ b, int n) {
    int i = blockIdx.x * blockDim.x + threadIdx.x;
    if (i < n) b[i] = a[i];
}
__global__ void k_hist(const int* __restrict__ dst, int* __restrict__ counts, int E) {
    int stride = gridDim.x * blockDim.x;
    for (int e = blockIdx.x * blockDim.x + threadIdx.x; e < E; e += stride)
        atomicAdd(&counts[dst[e]], 1);
}
__global__ __launch_bounds__(256) void k_bsum(const int* __restrict__ counts,
                                              int* __restrict__ bsum, int N) {
    __shared__ int ib[256];
    int b = blockIdx.x, t = threadIdx.x;
    int base = b * 1024 + t * 4;
    int s = 0;
    for (int i = 0; i < 4; ++i) { int g = base + i; if (g < N) s += counts[g]; }
    ib[t] = s; __syncthreads();
    for (int st = 128; st > 0; st >>= 1) { if (t < st) ib[t] += ib[t + st]; __syncthreads(); }
    if (t == 0) bsum[b] = ib[0];
}
__global__ void k_bscan(const int* __restrict__ bsum, int* __restrict__ bscan,
                        int* __restrict__ row_ptr, int NB, int N) {
    if (blockIdx.x == 0 && threadIdx.x == 0) {
        int run = 0;
        for (int b = 0; b < NB; ++b) { bscan[b] = run; run += bsum[b]; }
        row_ptr[N] = run;
    }
}
__global__ __launch_bounds__(256) void k_scan3(const int* __restrict__ counts,
                                               const int* __restrict__ bscan,
                                               int* __restrict__ row_ptr, int N) {
    __shared__ int ib[256];
    int b = blockIdx.x, t = threadIdx.x;
    int base = b * 1024 + t * 4;
    int c[4]; int ts = 0;
    for (int i = 0; i < 4; ++i) { int g = base + i; c[i] = (g < N) ? counts[g] : 0; ts += c[i]; }
    ib[t] = ts; __syncthreads();
    for (int st = 1; st < 256; st <<= 1) {
        int v = (t >= st) ? ib[t - st] : 0;
        __syncthreads();
        ib[t] += v;
        __syncthreads();
    }
    int run = ib[t] - ts + bscan[b];
    for (int i = 0; i < 4; ++i) { int g = base + i; if (g < N) row_ptr[g] = run; run += c[i]; }
}
__global__ void k_fill(const int* __restrict__ src, const int* __restrict__ dst,
                       int* __restrict__ cursor, int* __restrict__ out_src, int E) {
    int stride = gridDim.x * blockDim.x;
    for (int e = blockIdx.x * blockDim.x + threadIdx.x; e < E; e += stride) {
        int pos = atomicAdd(&cursor[dst[e]], 1);
        out_src[pos] = src[e];
    }
}

// ---------- K3: out = xt0[i] + sum_in xt0[src]; exp_map; fused log_map -> A1 ----------
__global__ __launch_bounds__(128) void k_agg(const float* __restrict__ xt0,
                                             const int* __restrict__ row_ptr,
                                             const int* __restrict__ srcl,
                                             float* __restrict__ A1, int N) {
    int i = blockIdx.x, t = threadIdx.x;
    float u = xt0[(size_t)i * 128 + t];
    int b = row_ptr[i], e = row_ptr[i + 1];
    for (int k = b; k < e; ++k) {
        int s = srcl[k];
        u += xt0[(size_t)s * 128 + t];
    }
    if (t == 0) u = 0.f;
    __shared__ float sred[128];
    float s1 = blockReduceSumF(u * u, sred);
    float n = sqrtf(fmaxf(s1 + EPSF, 1e-6f));
    float ncut = fminf(n, 50.f);
    float sh = sinhf(ncut);
    float tv = sh * u / n;
    float s2 = blockReduceSumF(tv * tv, sred);
    float first = sqrtf(1.0f + s2);
    // fused log_map_zero for layer-1 input
    float dist = arcosh_f(first + EPSF);
    float nrm = sqrtf(s2 + EPSF);
    float scl = dist / nrm;
    if (t >= 1) A1[(size_t)i * 128 + (t - 1)] = scl * tv;
    else        A1[(size_t)i * 128 + 127] = 0.f;  // pad
}

// ---------- SIMT fp32 GEMM: Y[M x ncols] = A[M x K] @ W[ncols x K]^T + bias ----------
__global__ __launch_bounds__(256) void k_gemm(const float* __restrict__ A, int lda,
                                              const float* __restrict__ W,
                                              const float* __restrict__ bias,
                                              float* __restrict__ Y, int ldy,
                                              int M, int K, int Kp, int ncols) {
    __shared__ float As[16][64];
    __shared__ float Bs[16][64];
    int tid = threadIdx.x;
    int bm = blockIdx.x * 64;
    int bn = blockIdx.y * 64;
    int tm = (tid & 15) * 4;
    int tn = (tid >> 4) * 4;
    int ar = tid >> 2;
    int ak = (tid & 3) * 4;
    int bj = tid >> 4;
    int bk = tid & 15;
    float acc[4][4] = {};
    for (int k0 = 0; k0 < Kp; k0 += 16) {
        float4 av = make_float4(0.f, 0.f, 0.f, 0.f);
        int grow = bm + ar;
        if (grow < M) av = *reinterpret_cast<const float4*>(A + (size_t)grow * lda + k0 + ak);
        As[ak + 0][ar] = av.x; As[ak + 1][ar] = av.y;
        As[ak + 2][ar] = av.z; As[ak + 3][ar] = av.w;
        int kk = k0 + bk;
#pragma unroll
        for (int i2 = 0; i2 < 4; ++i2) {
            int col = bn + bj + i2 * 16;
            float v = 0.f;
            if (col < ncols && kk < K) v = W[(size_t)col * K + kk];
            Bs[bk][bj + i2 * 16] = v;
        }
        __syncthreads();
#pragma unroll
        for (int kq = 0; kq < 16; ++kq) {
            float4 a = *reinterpret_cast<const float4*>(&As[kq][tm]);
            float4 b = *reinterpret_cast<const float4*>(&Bs[kq][tn]);
            float aa[4] = {a.x, a.y, a.z, a.w};
            float bb[4] = {b.x, b.y, b.z, b.w};
#pragma unroll
            for (int i = 0; i < 4; ++i)
#pragma unroll
                for (int j = 0; j < 4; ++j) acc[i][j] += aa[i] * bb[j];
        }
        __syncthreads();
    }
#pragma unroll
    for (int i = 0; i < 4; ++i) {
        int row = bm + tm + i;
        if (row >= M) continue;
#pragma unroll
        for (int j = 0; j < 4; ++j) {
            int col = bn + tn + j;
            if (col < ncols) Y[(size_t)row * ldy + col] = acc[i][j] + bias[col];
        }
    }
}

// ---------- Epilogue: exp_map (w/ allzero), log, relu, exp_map, fused next log ----------
// MODE 0: write tangent to A buffer (cols [0,ncols) + zero pad to ldo)
// MODE 1: write ht = [0, tangent] (in-place over Y allowed; stride ldo)
template <int MODE>
__global__ __launch_bounds__(256) void k_ep(const float* __restrict__ Y, int ldy, int ncols,
                                            float* __restrict__ out, int ldo, int N) {
    int i = blockIdx.x, t = threadIdx.x;
    const float* yr = Y + (size_t)i * ldy;
    int j0 = t, j1 = t + 256;
    float y0v = (j0 < ncols) ? yr[j0] : 0.f;
    float y1v = (j1 < ncols) ? yr[j1] : 0.f;
    __shared__ float sred[256];
    float s1 = blockReduceSumF(y0v * y0v + y1v * y1v, sred);
    float sab = blockReduceSumF(fabsf(y0v) + fabsf(y1v), sred);
    bool allz = (sab == 0.0f);
    // lorentz_linear: exp_map + where(all(mx==0), 0, h)
    float n = sqrtf(fmaxf(s1 + EPSF, 1e-6f));
    float ncut = fminf(n, 50.f);
    float sh = sinhf(ncut);
    float t0 = allz ? 0.f : sh * y0v / n;
    float t1 = allz ? 0.f : sh * y1v / n;
    float s2 = blockReduceSumF(t0 * t0 + t1 * t1, sred);
    float first = allz ? 0.f : sqrtf(1.0f + s2);
    // lorentz_act: log_map, relu
    float dist = arcosh_f(first + EPSF);
    float nrm = sqrtf(s2 + EPSF);
    float r0 = fmaxf(dist / nrm * t0, 0.f);
    float r1 = fmaxf(dist / nrm * t1, 0.f);
    float s3 = blockReduceSumF(r0 * r0 + r1 * r1, sred);
    // exp_map
    float n2 = sqrtf(fmaxf(s3 + EPSF, 1e-6f));
    float nc2 = fminf(n2, 50.f);
    float sh2 = sinhf(nc2);
    float u0 = sh2 * r0 / n2;
    float u1 = sh2 * r1 / n2;
    float s4 = blockReduceSumF(u0 * u0 + u1 * u1, sred);
    float first2 = sqrtf(1.0f + s4);
    // fused next-layer log_map_zero
    float dist2 = arcosh_f(first2 + EPSF);
    float nrm2 = sqrtf(s4 + EPSF);
    float sc2 = dist2 / nrm2;
    float* orow = out + (size_t)i * ldo;
    if (MODE == 0) {
        if (j0 < ncols) orow[j0] = sc2 * u0;
        if (j1 < ncols) orow[j1] = sc2 * u1;
        for (int j = ncols + t; j < ldo; j += 256) orow[j] = 0.f;
    } else {
        if (t == 0) orow[0] = 0.f;
        if (j0 < ncols) orow[1 + j0] = sc2 * u0;
        if (j1 < ncols) orow[1 + j1] = sc2 * u1;
    }
}

// ---------- mean partials (deterministic) ----------
__global__ __launch_bounds__(384) void k_mean(const float* __restrict__ ht,
                                              float* __restrict__ partials, int N, int chunk) {
    int b = blockIdx.x;
    int j = threadIdx.x;
    int lo = b * chunk;
    int hi = lo + chunk; if (hi > N) hi = N;
    float acc = 0.f;
    for (int n = lo; n < hi; ++n) acc += ht[(size_t)n * 384 + j];
    partials[(size_t)b * 384 + j] = acc;
}

// ---------- classifier head: hm -> h_classify, prob ----------
__global__ __launch_bounds__(128) void k_final(const float* __restrict__ partials, int nparts,
                                               const float* __restrict__ Wc,
                                               const float* __restrict__ bc,
                                               float* __restrict__ dout, int N, int ic, int oc) {
    __shared__ float hm[384];
    __shared__ float xt[384];
    __shared__ float sred[128];
    __shared__ float mx[16];
    int t = threadIdx.x;
    for (int j = t; j < 384; j += 128) {
        float s = 0.f;
        for (int b = 0; b < nparts; ++b) s += partials[(size_t)b * 384 + j];
        hm[j] = s / (float)N;
    }
    __syncthreads();
    if (t == 0) hm[0] = 0.f;
    __syncthreads();
    float ls = 0.f;
    for (int j = t; j < 384; j += 128) if (j >= 1) ls += hm[j] * hm[j];
    float ssum = blockReduceSumF(ls, sred);
    float nrm = sqrtf(ssum + EPSF);
    float dist = arcosh_f(0.0f + EPSF);  // hm[0] = 0
    float scl = dist / nrm;
    for (int k = t; k < ic; k += 128) xt[k] = scl * hm[k + 1];
    __syncthreads();
    if (t < oc) {
        float acc = bc[t];
        for (int k = 0; k < ic; ++k) acc += xt[k] * Wc[(size_t)t * ic + k];
        mx[t] = acc;
    }
    __syncthreads();
    if (t == 0) {
        float y[10], tt[10], lt[10], p[10], t3[10];
        float s1 = 0.f, sab = 0.f;
        for (int j = 0; j < oc; ++j) { y[j] = mx[j]; s1 += y[j] * y[j]; sab += fabsf(y[j]); }
        bool allz = (sab == 0.f);
        float n = sqrtf(fmaxf(s1 + EPSF, 1e-6f));
        float nc = fminf(n, 50.f);
        float sh = sinhf(nc);
        float s2 = 0.f;
        for (int j = 0; j < oc; ++j) { tt[j] = allz ? 0.f : sh * y[j] / n; s2 += tt[j] * tt[j]; }
        float first = allz ? 0.f : sqrtf(1.f + s2);
        dout[0] = first;
        for (int j = 0; j < oc; ++j) dout[1 + j] = tt[j];
        // prob = lorentz_act(h_classify, softmax)
        float dist2 = arcosh_f(first + EPSF);
        float nrm2 = sqrtf(s2 + EPSF);
        lt[0] = 0.f;
        for (int j = 0; j < oc; ++j) lt[1 + j] = dist2 / nrm2 * tt[j];
        float m = lt[0];
        for (int j = 1; j < 10; ++j) m = fmaxf(m, lt[j]);
        float es = 0.f;
        for (int j = 0; j < 10; ++j) { p[j] = expf(lt[j] - m); es += p[j]; }
        for (int j = 0; j < 10; ++j) p[j] /= es;
        p[0] = 0.f;
        float s3 = 0.f;
        for (int j = 1; j < 10; ++j) s3 += p[j] * p[j];
        float n3 = sqrtf(fmaxf(s3 + EPSF, 1e-6f));
        float nc3 = fminf(n3, 50.f);
        float sh3 = sinhf(nc3);
        float s4 = 0.f;
        for (int j = 1; j < 10; ++j) { t3[j] = sh3 * p[j] / n3; s4 += t3[j] * t3[j]; }
        dout[10] = sqrtf(1.f + s4);
        for (int j = 1; j < 10; ++j) dout[10 + j] = t3[j];
    }
}

extern "C" void kernel_launch(void* const* d_in, const int* in_sizes, int n_in,
                              void* d_out, int out_size, void* d_ws, size_t ws_size,
                              hipStream_t stream) {
    if (n_in < 10) return;
    const float* x   = (const float*)d_in[0];
    const int*   ei  = (const int*)d_in[1];
    const float* W0  = (const float*)d_in[2];
    const float* b0  = (const float*)d_in[3];
    const float* W1  = (const float*)d_in[4];
    const float* b1  = (const float*)d_in[5];
    const float* W2  = (const float*)d_in[6];
    const float* b2  = (const float*)d_in[7];
    const float* Wc  = (const float*)d_in[8];
    const float* bc  = (const float*)d_in[9];
    float* dout = (float*)d_out;

    int N = in_sizes[0] / 128;
    int E = in_sizes[1] / 2;
    int o1 = in_sizes[3];           // 127
    int i1 = in_sizes[2] / o1;      // 127
    int o2 = in_sizes[5];           // 255
    int i2 = in_sizes[4] / o2;      // 127
    int o3 = in_sizes[7];           // 383
    int i3 = in_sizes[6] / o3;      // 255
    int oc = in_sizes[9];           // 9
    int ic = in_sizes[8] / oc;      // 383

    const int* esrc = ei;
    const int* edst = ei + E;

    // workspace layout (~132 MB)
    char* ws = (char*)d_ws;
    auto alloc = [&](size_t bytes) {
        char* p = ws;
        ws += (bytes + 511) & ~(size_t)511;
        return p;
    };
    float* Q        = (float*)alloc((size_t)N * 256 * 4);  // A buffer (and xt0 in upper half)
    float* R        = (float*)alloc((size_t)N * 384 * 4);  // Y / ht buffer
    int*   counts   = (int*)alloc((size_t)N * 4);
    int*   row_ptr  = (int*)alloc((size_t)(N + 1) * 4);
    int*   cursor   = (int*)alloc((size_t)N * 4);
    int*   srcl     = (int*)alloc((size_t)E * 4);
    int*   bsum     = (int*)alloc(4096 * 4);
    int*   bscan    = (int*)alloc(4096 * 4);
    float* partials = (float*)alloc((size_t)256 * 384 * 4);
    (void)ws_size;

    float* xt0 = Q + (size_t)N * 128;  // upper half of Q
    float* A1  = Q;                    // lower half (written after xt0 consumed per-row)

    int zb = (N + 255) / 256;
    int NB = (N + 1023) / 1024;

    // 1. log_map_zero(x)
    k_log0<<<dim3(N), dim3(128), 0, stream>>>(x, xt0, N);
    // 2. CSR build
    k_zero_i<<<dim3(zb), dim3(256), 0, stream>>>(counts, N);
    k_hist<<<dim3(512), dim3(256), 0, stream>>>(edst, counts, E);
    k_bsum<<<dim3(NB), dim3(256), 0, stream>>>(counts, bsum, N);
    k_bscan<<<dim3(1), dim3(1), 0, stream>>>(bsum, bscan, row_ptr, NB, N);
    k_scan3<<<dim3(NB), dim3(256), 0, stream>>>(counts, bscan, row_ptr, N);
    k_copy_i<<<dim3(zb), dim3(256), 0, stream>>>(row_ptr, cursor, N);
    k_fill<<<dim3(512), dim3(256), 0, stream>>>(esrc, edst, cursor, srcl, E);
    // 3. aggregate + exp_map + fused log -> A1
    k_agg<<<dim3(N), dim3(128), 0, stream>>>(xt0, row_ptr, srcl, A1, N);
    // 4. layer 1
    k_gemm<<<dim3((N + 63) / 64, (o1 + 63) / 64), dim3(256), 0, stream>>>(
        A1, 128, W0, b0, R, 128, N, i1, 128, o1);
    k_ep<0><<<dim3(N), dim3(256), 0, stream>>>(R, 128, o1, Q, 128, N);
    // 5. layer 2
    k_gemm<<<dim3((N + 63) / 64, (o2 + 63) / 64), dim3(256), 0, stream>>>(
        Q, 128, W1, b1, R, 256, N, i2, 128, o2);
    k_ep<0><<<dim3(N), dim3(256), 0, stream>>>(R, 256, o2, Q, 256, N);
    // 6. layer 3
    k_gemm<<<dim3((N + 63) / 64, (o3 + 63) / 64), dim3(256), 0, stream>>>(
        Q, 256, W2, b2, R, 384, N, i3, 256, o3);
    k_ep<1><<<dim3(N), dim3(256), 0, stream>>>(R, 384, o3, R, 384, N);
    // 7. mean (deterministic two-stage)
    int chunk = (N + 255) / 256;
    k_mean<<<dim3(256), dim3(384), 0, stream>>>(R, partials, N, chunk);
    // 8. classifier head
    k_final<<<dim3(1), dim3(128), 0, stream>>>(partials, 256, Wc, bc, dout, N, ic, oc);
}

// Round 2
// 582.118 us; speedup vs baseline: 2.1882x; 2.1882x over previous
//
#include <hip/hip_runtime.h>
#include <math.h>

#define EPSF 1e-7f

typedef unsigned short ushort_t;
typedef __attribute__((ext_vector_type(8))) short bf16x8;
typedef __attribute__((ext_vector_type(4))) float f32x4;

__device__ __forceinline__ float arcosh_f(float x) {
    x = fmaxf(x, 1.0f + EPSF);
    return logf(x + sqrtf(x * x - 1.0f));
}

__device__ __forceinline__ unsigned short f2bf(float f) {
    union { float f; unsigned u; } c; c.f = f;
    unsigned r = c.u + 0x7FFFu + ((c.u >> 16) & 1u);
    return (unsigned short)(r >> 16);
}
__device__ __forceinline__ float bf2f(unsigned short u) {
    union { unsigned u; float f; } c; c.u = ((unsigned)u) << 16;
    return c.f;
}

__device__ __forceinline__ float wredsum(float v) {
#pragma unroll
    for (int off = 32; off; off >>= 1) v += __shfl_xor(v, off, 64);
    return v;
}

__device__ __forceinline__ void llds16(const void* g, void* l) {
    __builtin_amdgcn_global_load_lds((const __attribute__((address_space(1))) unsigned int*)g,
                                     (__attribute__((address_space(3))) unsigned int*)l,
                                     16, 0, 0);
}

// power-of-two blockDim reduce (k_final only)
__device__ __forceinline__ float blockReduceSumF(float v, float* sbuf) {
    int tid = threadIdx.x;
    sbuf[tid] = v;
    __syncthreads();
    for (int st = blockDim.x >> 1; st > 0; st >>= 1) {
        if (tid < st) sbuf[tid] += sbuf[tid + st];
        __syncthreads();
    }
    float r = sbuf[0];
    __syncthreads();
    return r;
}

// ---------- K1: xt0 = log_map_zero(x) -> bf16, stored in upper half of Abuf rows ----------
__global__ __launch_bounds__(64) void k_log0(const float* __restrict__ x,
                                             char* __restrict__ Abase, int N) {
    int i = blockIdx.x, t = threadIdx.x;
    float2 v = *reinterpret_cast<const float2*>(x + (size_t)i * 128 + 2 * t);
    float y0 = __shfl(v.x, 0, 64);
    float a0 = (t == 0) ? 0.f : v.x;
    float s = wredsum(a0 * a0 + v.y * v.y);
    float dist = arcosh_f(y0 + EPSF);
    float scl = dist / sqrtf(s + EPSF);
    ushort2 o;
    o.x = f2bf(scl * a0);
    o.y = f2bf(scl * v.y);
    *reinterpret_cast<ushort2*>(Abase + (size_t)i * 512 + 256 + 4 * t) = o;
}

// ---------- CSR build ----------
__global__ void k_zero_i(int* __restrict__ p, int n) {
    int i = blockIdx.x * blockDim.x + threadIdx.x;
    if (i < n) p[i] = 0;
}
__global__ void k_hist(const int* __restrict__ dst, int* __restrict__ counts, int E) {
    int stride = gridDim.x * blockDim.x;
    for (int e = blockIdx.x * blockDim.x + threadIdx.x; e < E; e += stride)
        atomicAdd(&counts[dst[e]], 1);
}
__global__ __launch_bounds__(256) void k_bsum(const int* __restrict__ counts,
                                              int* __restrict__ bsum, int N) {
    __shared__ int ib[256];
    int b = blockIdx.x, t = threadIdx.x;
    int base = b * 1024 + t * 4;
    int s = 0;
    for (int i = 0; i < 4; ++i) { int g = base + i; if (g < N) s += counts[g]; }
    ib[t] = s; __syncthreads();
    for (int st = 128; st > 0; st >>= 1) { if (t < st) ib[t] += ib[t + st]; __syncthreads(); }
    if (t == 0) bsum[b] = ib[0];
}
__global__ void k_bscan(const int* __restrict__ bsum, int* __restrict__ bscan,
                        int* __restrict__ row_ptr, int NB, int N) {
    if (blockIdx.x == 0 && threadIdx.x == 0) {
        int run = 0;
        for (int b = 0; b < NB; ++b) { bscan[b] = run; run += bsum[b]; }
        row_ptr[N] = run;
    }
}
__global__ __launch_bounds__(256) void k_scan3(const int* __restrict__ counts,
                                               const int* __restrict__ bscan,
                                               int* __restrict__ row_ptr,
                                               int* __restrict__ cursor, int N) {
    __shared__ int ib[256];
    int b = blockIdx.x, t = threadIdx.x;
    int base = b * 1024 + t * 4;
    int c[4]; int ts = 0;
    for (int i = 0; i < 4; ++i) { int g = base + i; c[i] = (g < N) ? counts[g] : 0; ts += c[i]; }
    ib[t] = ts; __syncthreads();
    for (int st = 1; st < 256; st <<= 1) {
        int v = (t >= st) ? ib[t - st] : 0;
        __syncthreads();
        ib[t] += v;
        __syncthreads();
    }
    int run = ib[t] - ts + bscan[b];
    for (int i = 0; i < 4; ++i) {
        int g = base + i;
        if (g < N) { row_ptr[g] = run; cursor[g] = run; }
        run += c[i];
    }
}
__global__ void k_fill(const int* __restrict__ src, const int* __restrict__ dst,
                       int* __restrict__ cursor, int* __restrict__ out_src, int E) {
    int stride = gridDim.x * blockDim.x;
    for (int e = blockIdx.x * blockDim.x + threadIdx.x; e < E; e += stride) {
        int pos = atomicAdd(&cursor[dst[e]], 1);
        out_src[pos] = src[e];
    }
}

// ---------- K3: agg + exp_map + fused log_map -> A1 (bf16, lower half of Abuf rows) ----------
__global__ __launch_bounds__(64) void k_agg(const char* __restrict__ Abase,
                                            const int* __restrict__ row_ptr,
                                            const int* __restrict__ srcl,
                                            ushort_t* __restrict__ Ab, int N) {
    int i = blockIdx.x, t = threadIdx.x;
    ushort2 sv = *reinterpret_cast<const ushort2*>(Abase + (size_t)i * 512 + 256 + 4 * t);
    float u0 = bf2f(sv.x), u1 = bf2f(sv.y);
    int b = row_ptr[i], e = row_ptr[i + 1];
    for (int k = b; k < e; ++k) {
        int s = srcl[k];
        ushort2 nv = *reinterpret_cast<const ushort2*>(Abase + (size_t)s * 512 + 256 + 4 * t);
        u0 += bf2f(nv.x);
        u1 += bf2f(nv.y);
    }
    if (t == 0) u0 = 0.f;
    float s1 = wredsum(u0 * u0 + u1 * u1);
    float n = sqrtf(fmaxf(s1 + EPSF, 1e-6f));
    float sh = sinhf(fminf(n, 50.f));
    float t0 = sh * u0 / n, t1 = sh * u1 / n;
    float s2 = wredsum(t0 * t0 + t1 * t1);
    float first = sqrtf(1.f + s2);
    float dist = arcosh_f(first + EPSF);
    float scl = dist / sqrtf(s2 + EPSF);
    ushort2 o;
    o.x = f2bf(scl * t0);
    o.y = f2bf(scl * t1);
    *reinterpret_cast<ushort2*>(Ab + (size_t)i * 256 + 2 * t) = o;
}

// ---------- W conversion: Wb[Npad][Kp] bf16, optional k-shift (layer 0) ----------
__global__ void k_convw(const float* __restrict__ W, ushort_t* __restrict__ Wb,
                        int ncols, int K, int Kp, int shift, int total) {
    int idx = blockIdx.x * blockDim.x + threadIdx.x;
    if (idx >= total) return;
    int o = idx / Kp, kk = idx - o * Kp;
    int ks = kk - shift;
    float v = 0.f;
    if (o < ncols && ks >= 0 && ks < K) v = W[(size_t)o * K + ks];
    Wb[idx] = f2bf(v);
}

// ---------- MFMA bf16 GEMM: Y[M x ncols] += A[M x Kp] @ W[Npad x Kp]^T + bias ----------
// 128x128 tile, BK=32, 4 waves, global_load_lds staging (m97 structure)
__global__ __launch_bounds__(256) void k_gemm(const ushort_t* __restrict__ Ab, int lda,
                                              const ushort_t* __restrict__ Wb, int ldw,
                                              const float* __restrict__ bias,
                                              float* __restrict__ Y, int ldy,
                                              int Kp, int ncols) {
    __shared__ ushort_t As[128 * 32];
    __shared__ ushort_t Bs[128 * 32];
    int tid = threadIdx.x;
    int lane = tid & 63, wv = tid >> 6;
    int bm = blockIdx.x * 128, bn = blockIdx.y * 128;
    int r = lane & 15, g4 = lane >> 4;
    int wr = (wv >> 1) * 64, wc = (wv & 1) * 64;

    f32x4 acc[4][4] = {};
    for (int k0 = 0; k0 < Kp; k0 += 32) {
#pragma unroll
        for (int ci = 0; ci < 2; ++ci) {
            int L = (wv * 2 + ci) * 1024 + lane * 16;
            int row = L >> 6, kb = L & 63;
            const char* ga = (const char*)Ab + ((size_t)(bm + row) * lda + k0) * 2 + kb;
            llds16(ga, (char*)As + (wv * 2 + ci) * 1024);
            const char* gb = (const char*)Wb + ((size_t)(bn + row) * ldw + k0) * 2 + kb;
            llds16(gb, (char*)Bs + (wv * 2 + ci) * 1024);
        }
        __syncthreads();
        bf16x8 af[4], bfr[4];
#pragma unroll
        for (int m = 0; m < 4; ++m)
            af[m] = *reinterpret_cast<const bf16x8*>((const char*)As + (wr + m * 16 + r) * 64 + g4 * 16);
#pragma unroll
        for (int n2 = 0; n2 < 4; ++n2)
            bfr[n2] = *reinterpret_cast<const bf16x8*>((const char*)Bs + (wc + n2 * 16 + r) * 64 + g4 * 16);
#pragma unroll
        for (int m = 0; m < 4; ++m)
#pragma unroll
            for (int n2 = 0; n2 < 4; ++n2)
                acc[m][n2] = __builtin_amdgcn_mfma_f32_16x16x32_bf16(af[m], bfr[n2], acc[m][n2], 0, 0, 0);
        __syncthreads();
    }
#pragma unroll
    for (int n2 = 0; n2 < 4; ++n2) {
        int col = bn + wc + n2 * 16 + r;
        if (col >= ncols) continue;
        float bv = bias[col];
#pragma unroll
        for (int m = 0; m < 4; ++m) {
#pragma unroll
            for (int j = 0; j < 4; ++j) {
                int row = bm + wr + m * 16 + g4 * 4 + j;
                Y[(size_t)row * ldy + col] = acc[m][n2][j] + bv;
            }
        }
    }
}

// ---------- Epilogue: exp_map(+allzero), log, relu, exp_map, fused next log. bf16 out ----------
template <int NCP>
__global__ __launch_bounds__(64) void k_ep(const float* __restrict__ Y, int ldy,
                                           ushort_t* __restrict__ out, int ldo, int N) {
    constexpr int CH = NCP / 128;
    constexpr int ncols = NCP - 1;
    int i = blockIdx.x, t = threadIdx.x;
    const float* yr = Y + (size_t)i * ldy;
    float y[2 * CH];
#pragma unroll
    for (int c = 0; c < CH; ++c) {
        float2 v = *reinterpret_cast<const float2*>(yr + c * 128 + 2 * t);
        y[2 * c] = v.x;
        y[2 * c + 1] = v.y;
    }
    if (t == 63) y[2 * CH - 1] = 0.f;  // col ncols pad
    float s1l = 0.f, sabl = 0.f;
#pragma unroll
    for (int q = 0; q < 2 * CH; ++q) { s1l += y[q] * y[q]; sabl += fabsf(y[q]); }
    float s1 = wredsum(s1l);
    float sab = wredsum(sabl);
    bool allz = (sab == 0.0f);
    float n = sqrtf(fmaxf(s1 + EPSF, 1e-6f));
    float sh = sinhf(fminf(n, 50.f));
    float fac = sh / n;
    float tq[2 * CH];
    float s2l = 0.f;
#pragma unroll
    for (int q = 0; q < 2 * CH; ++q) { tq[q] = allz ? 0.f : y[q] * fac; s2l += tq[q] * tq[q]; }
    float s2 = wredsum(s2l);
    float first = allz ? 0.f : sqrtf(1.f + s2);
    float dist = arcosh_f(first + EPSF);
    float rs = dist / sqrtf(s2 + EPSF);
    float rq[2 * CH];
    float s3l = 0.f;
#pragma unroll
    for (int q = 0; q < 2 * CH; ++q) { rq[q] = fmaxf(rs * tq[q], 0.f); s3l += rq[q] * rq[q]; }
    float s3 = wredsum(s3l);
    float n2 = sqrtf(fmaxf(s3 + EPSF, 1e-6f));
    float sh2 = sinhf(fminf(n2, 50.f));
    float fac2 = sh2 / n2;
    float uq[2 * CH];
    float s4l = 0.f;
#pragma unroll
    for (int q = 0; q < 2 * CH; ++q) { uq[q] = rq[q] * fac2; s4l += uq[q] * uq[q]; }
    float s4 = wredsum(s4l);
    float first2 = sqrtf(1.f + s4);
    float dist2 = arcosh_f(first2 + EPSF);
    float sc2 = dist2 / sqrtf(s4 + EPSF);
    ushort_t* orow = out + (size_t)i * ldo;
#pragma unroll
    for (int c = 0; c < CH; ++c) {
        ushort2 o;
        o.x = f2bf(sc2 * uq[2 * c]);
        o.y = f2bf(sc2 * uq[2 * c + 1]);
        *reinterpret_cast<ushort2*>(orow + c * 128 + 2 * t) = o;
    }
}

// ---------- mean partials (deterministic, bf16 in) ----------
__global__ __launch_bounds__(384) void k_mean(const char* __restrict__ Rbase,
                                              float* __restrict__ partials, int N, int chunk) {
    int b = blockIdx.x;
    int j = threadIdx.x;
    int lo = b * chunk;
    int hi = lo + chunk; if (hi > N) hi = N;
    float acc = 0.f;
    for (int n = lo; n < hi; ++n)
        acc += bf2f(*reinterpret_cast<const ushort_t*>(Rbase + (size_t)n * 1536 + 2 * j));
    partials[(size_t)b * 384 + j] = acc;
}

// ---------- classifier head ----------
__global__ __launch_bounds__(128) void k_final(const float* __restrict__ partials, int nparts,
                                               const float* __restrict__ Wc,
                                               const float* __restrict__ bc,
                                               float* __restrict__ dout, int N, int ic, int oc) {
    __shared__ float hm[384];
    __shared__ float xt[384];
    __shared__ float sred[128];
    __shared__ float mx[16];
    int t = threadIdx.x;
    for (int j = t; j < 384; j += 128) {
        float s = 0.f;
        for (int b = 0; b < nparts; ++b) s += partials[(size_t)b * 384 + j];
        hm[j] = s / (float)N;
    }
    __syncthreads();
    // hm[j] = mean tangent tail element j (j = 0..382); first element of hm is 0 implicitly
    float ls = 0.f;
    for (int j = t; j < 383; j += 128) ls += hm[j] * hm[j];
    float ssum = blockReduceSumF(ls, sred);
    float nrm = sqrtf(ssum + EPSF);
    float dist = arcosh_f(0.0f + EPSF);
    float scl = dist / nrm;
    for (int k = t; k < ic; k += 128) xt[k] = scl * hm[k];
    __syncthreads();
    if (t < oc) {
        float acc = bc[t];
        for (int k = 0; k < ic; ++k) acc += xt[k] * Wc[(size_t)t * ic + k];
        mx[t] = acc;
    }
    __syncthreads();
    if (t == 0) {
        float y[10], tt[10], lt[11], p[10], t3[10];
        float s1 = 0.f, sab = 0.f;
        for (int j = 0; j < oc; ++j) { y[j] = mx[j]; s1 += y[j] * y[j]; sab += fabsf(y[j]); }
        bool allz = (sab == 0.f);
        float n = sqrtf(fmaxf(s1 + EPSF, 1e-6f));
        float sh = sinhf(fminf(n, 50.f));
        float s2 = 0.f;
        for (int j = 0; j < oc; ++j) { tt[j] = allz ? 0.f : sh * y[j] / n; s2 += tt[j] * tt[j]; }
        float first = allz ? 0.f : sqrtf(1.f + s2);
        dout[0] = first;
        for (int j = 0; j < oc; ++j) dout[1 + j] = tt[j];
        float dist2 = arcosh_f(first + EPSF);
        float nrm2 = sqrtf(s2 + EPSF);
        lt[0] = 0.f;
        for (int j = 0; j < oc; ++j) lt[1 + j] = dist2 / nrm2 * tt[j];
        float m = lt[0];
        for (int j = 1; j <= oc; ++j) m = fmaxf(m, lt[j]);
        float es = 0.f;
        for (int j = 0; j <= oc; ++j) { p[j] = expf(lt[j] - m); es += p[j]; }
        for (int j = 0; j <= oc; ++j) p[j] /= es;
        p[0] = 0.f;
        float s3 = 0.f;
        for (int j = 1; j <= oc; ++j) s3 += p[j] * p[j];
        float n3 = sqrtf(fmaxf(s3 + EPSF, 1e-6f));
        float sh3 = sinhf(fminf(n3, 50.f));
        float s4 = 0.f;
        for (int j = 1; j <= oc; ++j) { t3[j] = sh3 * p[j] / n3; s4 += t3[j] * t3[j]; }
        dout[1 + oc] = sqrtf(1.f + s4);
        for (int j = 1; j <= oc; ++j) dout[1 + oc + j] = t3[j];
    }
}

extern "C" void kernel_launch(void* const* d_in, const int* in_sizes, int n_in,
                              void* d_out, int out_size, void* d_ws, size_t ws_size,
                              hipStream_t stream) {
    if (n_in < 10) return;
    const float* x   = (const float*)d_in[0];
    const int*   ei  = (const int*)d_in[1];
    const float* W0  = (const float*)d_in[2];
    const float* b0  = (const float*)d_in[3];
    const float* W1  = (const float*)d_in[4];
    const float* b1  = (const float*)d_in[5];
    const float* W2  = (const float*)d_in[6];
    const float* b2  = (const float*)d_in[7];
    const float* Wc  = (const float*)d_in[8];
    const float* bc  = (const float*)d_in[9];
    float* dout = (float*)d_out;

    int N = in_sizes[0] / 128;
    int E = in_sizes[1] / 2;
    int o1 = in_sizes[3];           // 127
    int i1 = in_sizes[2] / o1;      // 127
    int o2 = in_sizes[5];           // 255
    int i2 = in_sizes[4] / o2;      // 127
    int o3 = in_sizes[7];           // 383
    int i3 = in_sizes[6] / o3;      // 255
    int oc = in_sizes[9];           // 9
    int ic = in_sizes[8] / oc;      // 383

    int M_pad = ((N + 127) / 128) * 128;             // 50048
    int Kp1 = ((i1 + 31) / 32) * 32;                 // 128
    int Kp2 = ((i2 + 31) / 32) * 32;                 // 128
    int Kp3 = ((i3 + 31) / 32) * 32;                 // 256
    int Np1 = ((o1 + 127) / 128) * 128;              // 128
    int Np2 = ((o2 + 127) / 128) * 128;              // 256
    int Np3 = ((o3 + 127) / 128) * 128;              // 384

    const int* esrc = ei;
    const int* edst = ei + E;

    char* ws = (char*)d_ws;
    auto alloc = [&](size_t bytes) {
        char* p = ws;
        ws += (bytes + 511) & ~(size_t)511;
        return p;
    };
    ushort_t* Ab     = (ushort_t*)alloc((size_t)M_pad * 256 * 2);  // A (lo half) + xt0 (hi half)
    float*    R      = (float*)alloc((size_t)M_pad * 384 * 4);     // Y buffers / ht (bf16 in-place)
    ushort_t* Wb0    = (ushort_t*)alloc((size_t)Np1 * Kp1 * 2);
    ushort_t* Wb1    = (ushort_t*)alloc((size_t)Np2 * Kp2 * 2);
    ushort_t* Wb2    = (ushort_t*)alloc((size_t)Np3 * Kp3 * 2);
    int*      counts = (int*)alloc((size_t)N * 4);
    int*      row_ptr= (int*)alloc((size_t)(N + 1) * 4);
    int*      cursor = (int*)alloc((size_t)N * 4);
    int*      srcl   = (int*)alloc((size_t)E * 4);
    int*      bsum   = (int*)alloc(4096 * 4);
    int*      bscan  = (int*)alloc(4096 * 4);
    float*    partials = (float*)alloc((size_t)256 * 384 * 4);
    (void)ws_size;

    int zb = (N + 255) / 256;
    int NB = (N + 1023) / 1024;

    // weight conversion (bf16, padded; W0 k-shifted by 1 to absorb tail indexing)
    k_convw<<<dim3((Np1 * Kp1 + 255) / 256), dim3(256), 0, stream>>>(W0, Wb0, o1, i1, Kp1, 1, Np1 * Kp1);
    k_convw<<<dim3((Np2 * Kp2 + 255) / 256), dim3(256), 0, stream>>>(W1, Wb1, o2, i2, Kp2, 0, Np2 * Kp2);
    k_convw<<<dim3((Np3 * Kp3 + 255) / 256), dim3(256), 0, stream>>>(W2, Wb2, o3, i3, Kp3, 0, Np3 * Kp3);
    // 1. log_map_zero(x) -> xt0 bf16
    k_log0<<<dim3(N), dim3(64), 0, stream>>>(x, (char*)Ab, N);
    // 2. CSR build
    k_zero_i<<<dim3(zb), dim3(256), 0, stream>>>(counts, N);
    k_hist<<<dim3(512), dim3(256), 0, stream>>>(edst, counts, E);
    k_bsum<<<dim3(NB), dim3(256), 0, stream>>>(counts, bsum, N);
    k_bscan<<<dim3(1), dim3(1), 0, stream>>>(bsum, bscan, row_ptr, NB, N);
    k_scan3<<<dim3(NB), dim3(256), 0, stream>>>(counts, bscan, row_ptr, cursor, N);
    k_fill<<<dim3(512), dim3(256), 0, stream>>>(esrc, edst, cursor, srcl, E);
    // 3. aggregate + exp + fused log -> A (bf16)
    k_agg<<<dim3(N), dim3(64), 0, stream>>>((const char*)Ab, row_ptr, srcl, Ab, N);
    // 4. layer 1
    k_gemm<<<dim3(M_pad / 128, Np1 / 128), dim3(256), 0, stream>>>(Ab, 256, Wb0, Kp1, b0, R, 128, Kp1, o1);
    k_ep<128><<<dim3(N), dim3(64), 0, stream>>>(R, 128, Ab, 256, N);
    // 5. layer 2
    k_gemm<<<dim3(M_pad / 128, Np2 / 128), dim3(256), 0, stream>>>(Ab, 256, Wb1, Kp2, b1, R, 256, Kp2, o2);
    k_ep<256><<<dim3(N), dim3(64), 0, stream>>>(R, 256, Ab, 256, N);
    // 6. layer 3
    k_gemm<<<dim3(M_pad / 128, Np3 / 128), dim3(256), 0, stream>>>(Ab, 256, Wb2, Kp3, b2, R, 384, Kp3, o3);
    k_ep<384><<<dim3(N), dim3(64), 0, stream>>>(R, 384, (ushort_t*)R, 768, N);  // ht bf16 in-place
    // 7. deterministic two-stage mean
    int chunk = (N + 255) / 256;
    k_mean<<<dim3(256), dim3(384), 0, stream>>>((const char*)R, partials, N, chunk);
    // 8. classifier head
    k_final<<<dim3(1), dim3(128), 0, stream>>>(partials, 256, Wc, bc, dout, N, ic, oc);
}

// Round 3
// 434.988 us; speedup vs baseline: 2.9284x; 1.3382x over previous
//
#include <hip/hip_runtime.h>
#include <math.h>

#define EPSF 1e-7f

typedef unsigned short ushort_t;
typedef __attribute__((ext_vector_type(8))) short bf16x8;
typedef __attribute__((ext_vector_type(4))) float f32x4;

__device__ __forceinline__ float arcosh_f(float x) {
    x = fmaxf(x, 1.0f + EPSF);
    return logf(x + sqrtf(x * x - 1.0f));
}

__device__ __forceinline__ unsigned short f2bf(float f) {
    union { float f; unsigned u; } c; c.f = f;
    unsigned r = c.u + 0x7FFFu + ((c.u >> 16) & 1u);
    return (unsigned short)(r >> 16);
}
__device__ __forceinline__ float bf2f(unsigned short u) {
    union { unsigned u; float f; } c; c.u = ((unsigned)u) << 16;
    return c.f;
}

__device__ __forceinline__ float wredsum(float v) {
#pragma unroll
    for (int off = 32; off; off >>= 1) v += __shfl_xor(v, off, 64);
    return v;
}

__device__ __forceinline__ void llds16(const void* g, void* l) {
    __builtin_amdgcn_global_load_lds((const __attribute__((address_space(1))) unsigned int*)g,
                                     (__attribute__((address_space(3))) unsigned int*)l,
                                     16, 0, 0);
}

// ---------- K1: xt0 = log_map_zero(x) -> bf16, stored in upper half of Abuf rows ----------
__global__ __launch_bounds__(64) void k_log0(const float* __restrict__ x,
                                             char* __restrict__ Abase, int N) {
    int i = blockIdx.x, t = threadIdx.x;
    float2 v = *reinterpret_cast<const float2*>(x + (size_t)i * 128 + 2 * t);
    float y0 = __shfl(v.x, 0, 64);
    float a0 = (t == 0) ? 0.f : v.x;
    float s = wredsum(a0 * a0 + v.y * v.y);
    float dist = arcosh_f(y0 + EPSF);
    float scl = dist / sqrtf(s + EPSF);
    ushort2 o;
    o.x = f2bf(scl * a0);
    o.y = f2bf(scl * v.y);
    *reinterpret_cast<ushort2*>(Abase + (size_t)i * 512 + 256 + 4 * t) = o;
}

// ---------- CSR build ----------
__global__ void k_zero_i(int* __restrict__ p, int n) {
    int i = blockIdx.x * blockDim.x + threadIdx.x;
    if (i < n) p[i] = 0;
}
__global__ void k_hist(const int* __restrict__ dst, int* __restrict__ counts, int E) {
    int stride = gridDim.x * blockDim.x;
    for (int e = blockIdx.x * blockDim.x + threadIdx.x; e < E; e += stride)
        atomicAdd(&counts[dst[e]], 1);
}
__global__ __launch_bounds__(256) void k_bsum(const int* __restrict__ counts,
                                              int* __restrict__ bsum, int N) {
    __shared__ int ib[256];
    int b = blockIdx.x, t = threadIdx.x;
    int base = b * 1024 + t * 4;
    int s = 0;
    for (int i = 0; i < 4; ++i) { int g = base + i; if (g < N) s += counts[g]; }
    ib[t] = s; __syncthreads();
    for (int st = 128; st > 0; st >>= 1) { if (t < st) ib[t] += ib[t + st]; __syncthreads(); }
    if (t == 0) bsum[b] = ib[0];
}
__global__ void k_bscan(const int* __restrict__ bsum, int* __restrict__ bscan,
                        int* __restrict__ row_ptr, int NB, int N) {
    if (blockIdx.x == 0 && threadIdx.x == 0) {
        int run = 0;
        for (int b = 0; b < NB; ++b) { bscan[b] = run; run += bsum[b]; }
        row_ptr[N] = run;
    }
}
__global__ __launch_bounds__(256) void k_scan3(const int* __restrict__ counts,
                                               const int* __restrict__ bscan,
                                               int* __restrict__ row_ptr,
                                               int* __restrict__ cursor, int N) {
    __shared__ int ib[256];
    int b = blockIdx.x, t = threadIdx.x;
    int base = b * 1024 + t * 4;
    int c[4]; int ts = 0;
    for (int i = 0; i < 4; ++i) { int g = base + i; c[i] = (g < N) ? counts[g] : 0; ts += c[i]; }
    ib[t] = ts; __syncthreads();
    for (int st = 1; st < 256; st <<= 1) {
        int v = (t >= st) ? ib[t - st] : 0;
        __syncthreads();
        ib[t] += v;
        __syncthreads();
    }
    int run = ib[t] - ts + bscan[b];
    for (int i = 0; i < 4; ++i) {
        int g = base + i;
        if (g < N) { row_ptr[g] = run; cursor[g] = run; }
        run += c[i];
    }
}
__global__ void k_fill(const int* __restrict__ src, const int* __restrict__ dst,
                       int* __restrict__ cursor, int* __restrict__ out_src, int E) {
    int stride = gridDim.x * blockDim.x;
    for (int e = blockIdx.x * blockDim.x + threadIdx.x; e < E; e += stride) {
        int pos = atomicAdd(&cursor[dst[e]], 1);
        out_src[pos] = src[e];
    }
}

// ---------- K3: agg + exp_map + fused log_map -> A1 (bf16, lower half of Abuf rows) ----------
__global__ __launch_bounds__(64) void k_agg(const char* __restrict__ Abase,
                                            const int* __restrict__ row_ptr,
                                            const int* __restrict__ srcl,
                                            ushort_t* __restrict__ Ab, int N) {
    int i = blockIdx.x, t = threadIdx.x;
    ushort2 sv = *reinterpret_cast<const ushort2*>(Abase + (size_t)i * 512 + 256 + 4 * t);
    float u0 = bf2f(sv.x), u1 = bf2f(sv.y);
    int b = row_ptr[i], e = row_ptr[i + 1];
    for (int k = b; k < e; ++k) {
        int s = srcl[k];
        ushort2 nv = *reinterpret_cast<const ushort2*>(Abase + (size_t)s * 512 + 256 + 4 * t);
        u0 += bf2f(nv.x);
        u1 += bf2f(nv.y);
    }
    if (t == 0) u0 = 0.f;
    float s1 = wredsum(u0 * u0 + u1 * u1);
    float n = sqrtf(fmaxf(s1 + EPSF, 1e-6f));
    float sh = sinhf(fminf(n, 50.f));
    float t0 = sh * u0 / n, t1 = sh * u1 / n;
    float s2 = wredsum(t0 * t0 + t1 * t1);
    float first = sqrtf(1.f + s2);
    float dist = arcosh_f(first + EPSF);
    float scl = dist / sqrtf(s2 + EPSF);
    ushort2 o;
    o.x = f2bf(scl * t0);
    o.y = f2bf(scl * t1);
    *reinterpret_cast<ushort2*>(Ab + (size_t)i * 256 + 2 * t) = o;
}

// ---------- W conversion: Wb[Npad][Kp] bf16, optional k-shift (layer 0) ----------
__global__ void k_convw(const float* __restrict__ W, ushort_t* __restrict__ Wb,
                        int ncols, int K, int Kp, int shift, int total) {
    int idx = blockIdx.x * blockDim.x + threadIdx.x;
    if (idx >= total) return;
    int o = idx / Kp, kk = idx - o * Kp;
    int ks = kk - shift;
    float v = 0.f;
    if (o < ncols && ks >= 0 && ks < K) v = W[(size_t)o * K + ks];
    Wb[idx] = f2bf(v);
}

// ---------- MFMA bf16 GEMM: Y[M x ncols] = A[M x Kp] @ W[Npad x Kp]^T + bias ----------
__global__ __launch_bounds__(256) void k_gemm(const ushort_t* __restrict__ Ab, int lda,
                                              const ushort_t* __restrict__ Wb, int ldw,
                                              const float* __restrict__ bias,
                                              float* __restrict__ Y, int ldy,
                                              int Kp, int ncols) {
    __shared__ ushort_t As[128 * 32];
    __shared__ ushort_t Bs[128 * 32];
    int tid = threadIdx.x;
    int lane = tid & 63, wv = tid >> 6;
    int bm = blockIdx.x * 128, bn = blockIdx.y * 128;
    int r = lane & 15, g4 = lane >> 4;
    int wr = (wv >> 1) * 64, wc = (wv & 1) * 64;

    f32x4 acc[4][4] = {};
    for (int k0 = 0; k0 < Kp; k0 += 32) {
#pragma unroll
        for (int ci = 0; ci < 2; ++ci) {
            int L = (wv * 2 + ci) * 1024 + lane * 16;
            int row = L >> 6, kb = L & 63;
            const char* ga = (const char*)Ab + ((size_t)(bm + row) * lda + k0) * 2 + kb;
            llds16(ga, (char*)As + (wv * 2 + ci) * 1024);
            const char* gb = (const char*)Wb + ((size_t)(bn + row) * ldw + k0) * 2 + kb;
            llds16(gb, (char*)Bs + (wv * 2 + ci) * 1024);
        }
        __syncthreads();
        bf16x8 af[4], bfr[4];
#pragma unroll
        for (int m = 0; m < 4; ++m)
            af[m] = *reinterpret_cast<const bf16x8*>((const char*)As + (wr + m * 16 + r) * 64 + g4 * 16);
#pragma unroll
        for (int n2 = 0; n2 < 4; ++n2)
            bfr[n2] = *reinterpret_cast<const bf16x8*>((const char*)Bs + (wc + n2 * 16 + r) * 64 + g4 * 16);
#pragma unroll
        for (int m = 0; m < 4; ++m)
#pragma unroll
            for (int n2 = 0; n2 < 4; ++n2)
                acc[m][n2] = __builtin_amdgcn_mfma_f32_16x16x32_bf16(af[m], bfr[n2], acc[m][n2], 0, 0, 0);
        __syncthreads();
    }
#pragma unroll
    for (int n2 = 0; n2 < 4; ++n2) {
        int col = bn + wc + n2 * 16 + r;
        if (col >= ncols) continue;
        float bv = bias[col];
#pragma unroll
        for (int m = 0; m < 4; ++m) {
#pragma unroll
            for (int j = 0; j < 4; ++j) {
                int row = bm + wr + m * 16 + g4 * 4 + j;
                Y[(size_t)row * ldy + col] = acc[m][n2][j] + bv;
            }
        }
    }
}

// ---------- Epilogue: exp_map(+allzero), log, relu, exp_map, fused next log. bf16 out ----------
template <int NCP>
__global__ __launch_bounds__(64) void k_ep(const float* __restrict__ Y, int ldy,
                                           ushort_t* __restrict__ out, int ldo, int N) {
    constexpr int CH = NCP / 128;
    int i = blockIdx.x, t = threadIdx.x;
    const float* yr = Y + (size_t)i * ldy;
    float y[2 * CH];
#pragma unroll
    for (int c = 0; c < CH; ++c) {
        float2 v = *reinterpret_cast<const float2*>(yr + c * 128 + 2 * t);
        y[2 * c] = v.x;
        y[2 * c + 1] = v.y;
    }
    if (t == 63) y[2 * CH - 1] = 0.f;  // col ncols pad
    float s1l = 0.f, sabl = 0.f;
#pragma unroll
    for (int q = 0; q < 2 * CH; ++q) { s1l += y[q] * y[q]; sabl += fabsf(y[q]); }
    float s1 = wredsum(s1l);
    float sab = wredsum(sabl);
    bool allz = (sab == 0.0f);
    float n = sqrtf(fmaxf(s1 + EPSF, 1e-6f));
    float sh = sinhf(fminf(n, 50.f));
    float fac = sh / n;
    float tq[2 * CH];
    float s2l = 0.f;
#pragma unroll
    for (int q = 0; q < 2 * CH; ++q) { tq[q] = allz ? 0.f : y[q] * fac; s2l += tq[q] * tq[q]; }
    float s2 = wredsum(s2l);
    float first = allz ? 0.f : sqrtf(1.f + s2);
    float dist = arcosh_f(first + EPSF);
    float rs = dist / sqrtf(s2 + EPSF);
    float rq[2 * CH];
    float s3l = 0.f;
#pragma unroll
    for (int q = 0; q < 2 * CH; ++q) { rq[q] = fmaxf(rs * tq[q], 0.f); s3l += rq[q] * rq[q]; }
    float s3 = wredsum(s3l);
    float n2 = sqrtf(fmaxf(s3 + EPSF, 1e-6f));
    float sh2 = sinhf(fminf(n2, 50.f));
    float fac2 = sh2 / n2;
    float uq[2 * CH];
    float s4l = 0.f;
#pragma unroll
    for (int q = 0; q < 2 * CH; ++q) { uq[q] = rq[q] * fac2; s4l += uq[q] * uq[q]; }
    float s4 = wredsum(s4l);
    float first2 = sqrtf(1.f + s4);
    float dist2 = arcosh_f(first2 + EPSF);
    float sc2 = dist2 / sqrtf(s4 + EPSF);
    ushort_t* orow = out + (size_t)i * ldo;
#pragma unroll
    for (int c = 0; c < CH; ++c) {
        ushort2 o;
        o.x = f2bf(sc2 * uq[2 * c]);
        o.y = f2bf(sc2 * uq[2 * c + 1]);
        *reinterpret_cast<ushort2*>(orow + c * 128 + 2 * t) = o;
    }
}

// ---------- mean partials (deterministic, bf16 in) ----------
__global__ __launch_bounds__(384) void k_mean(const char* __restrict__ Rbase,
                                              float* __restrict__ partials, int N, int chunk) {
    int b = blockIdx.x;
    int j = threadIdx.x;
    int lo = b * chunk;
    int hi = lo + chunk; if (hi > N) hi = N;
    float acc = 0.f;
    for (int n = lo; n < hi; ++n)
        acc += bf2f(*reinterpret_cast<const ushort_t*>(Rbase + (size_t)n * 1536 + 2 * j));
    partials[(size_t)b * 384 + j] = acc;
}

// ---------- stage-2 mean reduce: one block per feature j ----------
__global__ __launch_bounds__(256) void k_mred(const float* __restrict__ partials,
                                              float* __restrict__ hm, int nparts, int N) {
    __shared__ float sb[256];
    int j = blockIdx.x, t = threadIdx.x;
    float v = (t < nparts) ? partials[(size_t)t * 384 + j] : 0.f;
    sb[t] = v; __syncthreads();
    for (int st = 128; st > 0; st >>= 1) { if (t < st) sb[t] += sb[t + st]; __syncthreads(); }
    if (t == 0) hm[j] = sb[0] / (float)N;
}

// ---------- classifier head: single wave, parallel loads ----------
__global__ __launch_bounds__(64) void k_head(const float* __restrict__ hm,
                                             const float* __restrict__ Wc,
                                             const float* __restrict__ bc,
                                             float* __restrict__ dout, int ic, int oc) {
    int t = threadIdx.x;
    float h[6];
    float ss = 0.f;
#pragma unroll
    for (int c = 0; c < 6; ++c) {
        int j = t + 64 * c;
        h[c] = (j < ic) ? hm[j] : 0.f;
        ss += h[c] * h[c];
    }
    float ssum = wredsum(ss);
    float dist = arcosh_f(0.0f + EPSF);  // hm[0] (time component) = 0
    float scl = dist / sqrtf(ssum + EPSF);
    float mxv[9];
#pragma unroll
    for (int o = 0; o < 9; ++o) {
        float p = 0.f;
        if (o < oc) {
#pragma unroll
            for (int c = 0; c < 6; ++c) {
                int j = t + 64 * c;
                if (j < ic) p += h[c] * Wc[(size_t)o * ic + j];
            }
        }
        float s = wredsum(p);
        mxv[o] = (o < oc) ? (scl * s + bc[o]) : 0.f;
    }
    if (t == 0) {
        float y[10], tt[10], lt[11], p[11], t3[11];
        float s1 = 0.f, sab = 0.f;
        for (int j = 0; j < 9; ++j) {
            y[j] = (j < oc) ? mxv[j] : 0.f;
            s1 += y[j] * y[j]; sab += fabsf(y[j]);
        }
        bool allz = (sab == 0.f);
        float n = sqrtf(fmaxf(s1 + EPSF, 1e-6f));
        float sh = sinhf(fminf(n, 50.f));
        float s2 = 0.f;
        for (int j = 0; j < oc; ++j) { tt[j] = allz ? 0.f : sh * y[j] / n; s2 += tt[j] * tt[j]; }
        float first = allz ? 0.f : sqrtf(1.f + s2);
        dout[0] = first;
        for (int j = 0; j < oc; ++j) dout[1 + j] = tt[j];
        float dist2 = arcosh_f(first + EPSF);
        float nrm2 = sqrtf(s2 + EPSF);
        lt[0] = 0.f;
        for (int j = 0; j < oc; ++j) lt[1 + j] = dist2 / nrm2 * tt[j];
        float m = lt[0];
        for (int j = 1; j <= oc; ++j) m = fmaxf(m, lt[j]);
        float es = 0.f;
        for (int j = 0; j <= oc; ++j) { p[j] = expf(lt[j] - m); es += p[j]; }
        for (int j = 0; j <= oc; ++j) p[j] /= es;
        p[0] = 0.f;
        float s3 = 0.f;
        for (int j = 1; j <= oc; ++j) s3 += p[j] * p[j];
        float n3 = sqrtf(fmaxf(s3 + EPSF, 1e-6f));
        float sh3 = sinhf(fminf(n3, 50.f));
        float s4 = 0.f;
        for (int j = 1; j <= oc; ++j) { t3[j] = sh3 * p[j] / n3; s4 += t3[j] * t3[j]; }
        dout[1 + oc] = sqrtf(1.f + s4);
        for (int j = 1; j <= oc; ++j) dout[1 + oc + j] = t3[j];
    }
}

extern "C" void kernel_launch(void* const* d_in, const int* in_sizes, int n_in,
                              void* d_out, int out_size, void* d_ws, size_t ws_size,
                              hipStream_t stream) {
    if (n_in < 10) return;
    const float* x   = (const float*)d_in[0];
    const int*   ei  = (const int*)d_in[1];
    const float* W0  = (const float*)d_in[2];
    const float* b0  = (const float*)d_in[3];
    const float* W1  = (const float*)d_in[4];
    const float* b1  = (const float*)d_in[5];
    const float* W2  = (const float*)d_in[6];
    const float* b2  = (const float*)d_in[7];
    const float* Wc  = (const float*)d_in[8];
    const float* bc  = (const float*)d_in[9];
    float* dout = (float*)d_out;

    int N = in_sizes[0] / 128;
    int E = in_sizes[1] / 2;
    int o1 = in_sizes[3];           // 127
    int i1 = in_sizes[2] / o1;      // 127
    int o2 = in_sizes[5];           // 255
    int i2 = in_sizes[4] / o2;      // 127
    int o3 = in_sizes[7];           // 383
    int i3 = in_sizes[6] / o3;      // 255
    int oc = in_sizes[9];           // 9
    int ic = in_sizes[8] / oc;      // 383

    int M_pad = ((N + 127) / 128) * 128;             // 50048
    int Kp1 = ((i1 + 31) / 32) * 32;                 // 128
    int Kp2 = ((i2 + 31) / 32) * 32;                 // 128
    int Kp3 = ((i3 + 31) / 32) * 32;                 // 256
    int Np1 = ((o1 + 127) / 128) * 128;              // 128
    int Np2 = ((o2 + 127) / 128) * 128;              // 256
    int Np3 = ((o3 + 127) / 128) * 128;              // 384

    const int* esrc = ei;
    const int* edst = ei + E;

    char* ws = (char*)d_ws;
    auto alloc = [&](size_t bytes) {
        char* p = ws;
        ws += (bytes + 511) & ~(size_t)511;
        return p;
    };
    ushort_t* Ab     = (ushort_t*)alloc((size_t)M_pad * 256 * 2);  // A (lo half) + xt0 (hi half)
    float*    R      = (float*)alloc((size_t)M_pad * 384 * 4);     // Y buffers / ht (bf16 in-place)
    ushort_t* Wb0    = (ushort_t*)alloc((size_t)Np1 * Kp1 * 2);
    ushort_t* Wb1    = (ushort_t*)alloc((size_t)Np2 * Kp2 * 2);
    ushort_t* Wb2    = (ushort_t*)alloc((size_t)Np3 * Kp3 * 2);
    int*      counts = (int*)alloc((size_t)N * 4);
    int*      row_ptr= (int*)alloc((size_t)(N + 1) * 4);
    int*      cursor = (int*)alloc((size_t)N * 4);
    int*      srcl   = (int*)alloc((size_t)E * 4);
    int*      bsum   = (int*)alloc(4096 * 4);
    int*      bscan  = (int*)alloc(4096 * 4);
    float*    partials = (float*)alloc((size_t)256 * 384 * 4);
    float*    hmbuf  = (float*)alloc(512 * 4);
    (void)ws_size;

    int zb = (N + 255) / 256;
    int NB = (N + 1023) / 1024;

    // weight conversion (bf16, padded; W0 k-shifted by 1 to absorb tail indexing)
    k_convw<<<dim3((Np1 * Kp1 + 255) / 256), dim3(256), 0, stream>>>(W0, Wb0, o1, i1, Kp1, 1, Np1 * Kp1);
    k_convw<<<dim3((Np2 * Kp2 + 255) / 256), dim3(256), 0, stream>>>(W1, Wb1, o2, i2, Kp2, 0, Np2 * Kp2);
    k_convw<<<dim3((Np3 * Kp3 + 255) / 256), dim3(256), 0, stream>>>(W2, Wb2, o3, i3, Kp3, 0, Np3 * Kp3);
    // 1. log_map_zero(x) -> xt0 bf16
    k_log0<<<dim3(N), dim3(64), 0, stream>>>(x, (char*)Ab, N);
    // 2. CSR build
    k_zero_i<<<dim3(zb), dim3(256), 0, stream>>>(counts, N);
    k_hist<<<dim3(512), dim3(256), 0, stream>>>(edst, counts, E);
    k_bsum<<<dim3(NB), dim3(256), 0, stream>>>(counts, bsum, N);
    k_bscan<<<dim3(1), dim3(1), 0, stream>>>(bsum, bscan, row_ptr, NB, N);
    k_scan3<<<dim3(NB), dim3(256), 0, stream>>>(counts, bscan, row_ptr, cursor, N);
    k_fill<<<dim3(512), dim3(256), 0, stream>>>(esrc, edst, cursor, srcl, E);
    // 3. aggregate + exp + fused log -> A (bf16)
    k_agg<<<dim3(N), dim3(64), 0, stream>>>((const char*)Ab, row_ptr, srcl, Ab, N);
    // 4. layer 1
    k_gemm<<<dim3(M_pad / 128, Np1 / 128), dim3(256), 0, stream>>>(Ab, 256, Wb0, Kp1, b0, R, 128, Kp1, o1);
    k_ep<128><<<dim3(N), dim3(64), 0, stream>>>(R, 128, Ab, 256, N);
    // 5. layer 2
    k_gemm<<<dim3(M_pad / 128, Np2 / 128), dim3(256), 0, stream>>>(Ab, 256, Wb1, Kp2, b1, R, 256, Kp2, o2);
    k_ep<256><<<dim3(N), dim3(64), 0, stream>>>(R, 256, Ab, 256, N);
    // 6. layer 3
    k_gemm<<<dim3(M_pad / 128, Np3 / 128), dim3(256), 0, stream>>>(Ab, 256, Wb2, Kp3, b2, R, 384, Kp3, o3);
    k_ep<384><<<dim3(N), dim3(64), 0, stream>>>(R, 384, (ushort_t*)R, 768, N);  // ht bf16 in-place
    // 7. deterministic mean: stage 1 partials, stage 2 per-feature tree
    int chunk = (N + 255) / 256;
    k_mean<<<dim3(256), dim3(384), 0, stream>>>((const char*)R, partials, N, chunk);
    k_mred<<<dim3(383), dim3(256), 0, stream>>>(partials, hmbuf, 256, N);
    // 8. classifier head (single wave, parallel loads)
    k_head<<<dim3(1), dim3(64), 0, stream>>>(hmbuf, Wc, bc, dout, ic, oc);
}

// Round 4
// 415.081 us; speedup vs baseline: 3.0688x; 1.0480x over previous
//
#include <hip/hip_runtime.h>
#include <math.h>

#define EPSF 1e-7f

typedef unsigned short ushort_t;
typedef __attribute__((ext_vector_type(8))) short bf16x8;
typedef __attribute__((ext_vector_type(4))) float f32x4;

__device__ __forceinline__ float arcosh_f(float x) {
    x = fmaxf(x, 1.0f + EPSF);
    return logf(x + sqrtf(x * x - 1.0f));
}

__device__ __forceinline__ unsigned short f2bf(float f) {
    union { float f; unsigned u; } c; c.f = f;
    unsigned r = c.u + 0x7FFFu + ((c.u >> 16) & 1u);
    return (unsigned short)(r >> 16);
}
__device__ __forceinline__ float bf2f(unsigned short u) {
    union { unsigned u; float f; } c; c.u = ((unsigned)u) << 16;
    return c.f;
}

__device__ __forceinline__ float wredsum(float v) {
#pragma unroll
    for (int off = 32; off; off >>= 1) v += __shfl_xor(v, off, 64);
    return v;
}

__device__ __forceinline__ void llds16(const void* g, void* l) {
    __builtin_amdgcn_global_load_lds((const __attribute__((address_space(1))) unsigned int*)g,
                                     (__attribute__((address_space(3))) unsigned int*)l,
                                     16, 0, 0);
}

// ---------- K1: xt0 = log_map_zero(x) -> bf16, stored in upper half of Abuf rows ----------
__global__ __launch_bounds__(64) void k_log0(const float* __restrict__ x,
                                             char* __restrict__ Abase, int N) {
    int i = blockIdx.x, t = threadIdx.x;
    float2 v = *reinterpret_cast<const float2*>(x + (size_t)i * 128 + 2 * t);
    float y0 = __shfl(v.x, 0, 64);
    float a0 = (t == 0) ? 0.f : v.x;
    float s = wredsum(a0 * a0 + v.y * v.y);
    float dist = arcosh_f(y0 + EPSF);
    float scl = dist / sqrtf(s + EPSF);
    ushort2 o;
    o.x = f2bf(scl * a0);
    o.y = f2bf(scl * v.y);
    *reinterpret_cast<ushort2*>(Abase + (size_t)i * 512 + 256 + 4 * t) = o;
}

// ---------- CSR build ----------
__global__ void k_zero_i(int* __restrict__ p, int n) {
    int i = blockIdx.x * blockDim.x + threadIdx.x;
    if (i < n) p[i] = 0;
}
__global__ void k_hist(const int* __restrict__ dst, int* __restrict__ counts, int E) {
    int e = blockIdx.x * blockDim.x + threadIdx.x;
    if (e < E) atomicAdd(&counts[dst[e]], 1);
}
__global__ __launch_bounds__(256) void k_bsum(const int* __restrict__ counts,
                                              int* __restrict__ bsum, int N) {
    __shared__ int ib[256];
    int b = blockIdx.x, t = threadIdx.x;
    int base = b * 1024 + t * 4;
    int s = 0;
    for (int i = 0; i < 4; ++i) { int g = base + i; if (g < N) s += counts[g]; }
    ib[t] = s; __syncthreads();
    for (int st = 128; st > 0; st >>= 1) { if (t < st) ib[t] += ib[t + st]; __syncthreads(); }
    if (t == 0) bsum[b] = ib[0];
}
__global__ void k_bscan(const int* __restrict__ bsum, int* __restrict__ bscan,
                        int* __restrict__ row_ptr, int NB, int N) {
    if (blockIdx.x == 0 && threadIdx.x == 0) {
        int run = 0;
        for (int b = 0; b < NB; ++b) { bscan[b] = run; run += bsum[b]; }
        row_ptr[N] = run;
    }
}
__global__ __launch_bounds__(256) void k_scan3(const int* __restrict__ counts,
                                               const int* __restrict__ bscan,
                                               int* __restrict__ row_ptr,
                                               int* __restrict__ cursor, int N) {
    __shared__ int ib[256];
    int b = blockIdx.x, t = threadIdx.x;
    int base = b * 1024 + t * 4;
    int c[4]; int ts = 0;
    for (int i = 0; i < 4; ++i) { int g = base + i; c[i] = (g < N) ? counts[g] : 0; ts += c[i]; }
    ib[t] = ts; __syncthreads();
    for (int st = 1; st < 256; st <<= 1) {
        int v = (t >= st) ? ib[t - st] : 0;
        __syncthreads();
        ib[t] += v;
        __syncthreads();
    }
    int run = ib[t] - ts + bscan[b];
    for (int i = 0; i < 4; ++i) {
        int g = base + i;
        if (g < N) { row_ptr[g] = run; cursor[g] = run; }
        run += c[i];
    }
}
__global__ void k_fill(const int* __restrict__ src, const int* __restrict__ dst,
                       int* __restrict__ cursor, int* __restrict__ out_src, int E) {
    int e = blockIdx.x * blockDim.x + threadIdx.x;
    if (e < E) {
        int pos = atomicAdd(&cursor[dst[e]], 1);
        out_src[pos] = src[e];
    }
}

// ---------- K3: agg + exp_map + fused log_map -> A1 (bf16, lower half of Abuf rows) ----------
__global__ __launch_bounds__(64) void k_agg(const char* __restrict__ Abase,
                                            const int* __restrict__ row_ptr,
                                            const int* __restrict__ srcl,
                                            ushort_t* __restrict__ Ab, int N) {
    int i = blockIdx.x, t = threadIdx.x;
    ushort2 sv = *reinterpret_cast<const ushort2*>(Abase + (size_t)i * 512 + 256 + 4 * t);
    float u0 = bf2f(sv.x), u1 = bf2f(sv.y);
    int b = row_ptr[i], e = row_ptr[i + 1];
    for (int k = b; k < e; ++k) {
        int s = srcl[k];
        ushort2 nv = *reinterpret_cast<const ushort2*>(Abase + (size_t)s * 512 + 256 + 4 * t);
        u0 += bf2f(nv.x);
        u1 += bf2f(nv.y);
    }
    if (t == 0) u0 = 0.f;
    float s1 = wredsum(u0 * u0 + u1 * u1);
    float n = sqrtf(fmaxf(s1 + EPSF, 1e-6f));
    float sh = sinhf(fminf(n, 50.f));
    float t0 = sh * u0 / n, t1 = sh * u1 / n;
    float s2 = wredsum(t0 * t0 + t1 * t1);
    float first = sqrtf(1.f + s2);
    float dist = arcosh_f(first + EPSF);
    float scl = dist / sqrtf(s2 + EPSF);
    ushort2 o;
    o.x = f2bf(scl * t0);
    o.y = f2bf(scl * t1);
    *reinterpret_cast<ushort2*>(Ab + (size_t)i * 256 + 2 * t) = o;
}

// ---------- W conversion: Wb[Npad][Kp] bf16, optional k-shift (layer 0) ----------
__global__ void k_convw(const float* __restrict__ W, ushort_t* __restrict__ Wb,
                        int ncols, int K, int Kp, int shift, int total) {
    int idx = blockIdx.x * blockDim.x + threadIdx.x;
    if (idx >= total) return;
    int o = idx / Kp, kk = idx - o * Kp;
    int ks = kk - shift;
    float v = 0.f;
    if (o < ncols && ks >= 0 && ks < K) v = W[(size_t)o * K + ks];
    Wb[idx] = f2bf(v);
}

// ---------- MFMA bf16 GEMM: Y[M x ncols] = A[M x Kp] @ W[Npad x Kp]^T + bias ----------
__global__ __launch_bounds__(256) void k_gemm(const ushort_t* __restrict__ Ab, int lda,
                                              const ushort_t* __restrict__ Wb, int ldw,
                                              const float* __restrict__ bias,
                                              float* __restrict__ Y, int ldy,
                                              int Kp, int ncols) {
    __shared__ ushort_t As[128 * 32];
    __shared__ ushort_t Bs[128 * 32];
    int tid = threadIdx.x;
    int lane = tid & 63, wv = tid >> 6;
    int bm = blockIdx.x * 128, bn = blockIdx.y * 128;
    int r = lane & 15, g4 = lane >> 4;
    int wr = (wv >> 1) * 64, wc = (wv & 1) * 64;

    f32x4 acc[4][4] = {};
    for (int k0 = 0; k0 < Kp; k0 += 32) {
#pragma unroll
        for (int ci = 0; ci < 2; ++ci) {
            int L = (wv * 2 + ci) * 1024 + lane * 16;
            int row = L >> 6, kb = L & 63;
            const char* ga = (const char*)Ab + ((size_t)(bm + row) * lda + k0) * 2 + kb;
            llds16(ga, (char*)As + (wv * 2 + ci) * 1024);
            const char* gb = (const char*)Wb + ((size_t)(bn + row) * ldw + k0) * 2 + kb;
            llds16(gb, (char*)Bs + (wv * 2 + ci) * 1024);
        }
        __syncthreads();
        bf16x8 af[4], bfr[4];
#pragma unroll
        for (int m = 0; m < 4; ++m)
            af[m] = *reinterpret_cast<const bf16x8*>((const char*)As + (wr + m * 16 + r) * 64 + g4 * 16);
#pragma unroll
        for (int n2 = 0; n2 < 4; ++n2)
            bfr[n2] = *reinterpret_cast<const bf16x8*>((const char*)Bs + (wc + n2 * 16 + r) * 64 + g4 * 16);
#pragma unroll
        for (int m = 0; m < 4; ++m)
#pragma unroll
            for (int n2 = 0; n2 < 4; ++n2)
                acc[m][n2] = __builtin_amdgcn_mfma_f32_16x16x32_bf16(af[m], bfr[n2], acc[m][n2], 0, 0, 0);
        __syncthreads();
    }
#pragma unroll
    for (int n2 = 0; n2 < 4; ++n2) {
        int col = bn + wc + n2 * 16 + r;
        if (col >= ncols) continue;
        float bv = bias[col];
#pragma unroll
        for (int m = 0; m < 4; ++m) {
#pragma unroll
            for (int j = 0; j < 4; ++j) {
                int row = bm + wr + m * 16 + g4 * 4 + j;
                Y[(size_t)row * ldy + col] = acc[m][n2][j] + bv;
            }
        }
    }
}

// ---------- Epilogue: exp_map(+allzero), log, relu, exp_map, fused next log. bf16 out ----------
template <int NCP>
__global__ __launch_bounds__(64) void k_ep(const float* __restrict__ Y, int ldy,
                                           ushort_t* __restrict__ out, int ldo, int N) {
    constexpr int CH = NCP / 128;
    int i = blockIdx.x, t = threadIdx.x;
    const float* yr = Y + (size_t)i * ldy;
    float y[2 * CH];
#pragma unroll
    for (int c = 0; c < CH; ++c) {
        float2 v = *reinterpret_cast<const float2*>(yr + c * 128 + 2 * t);
        y[2 * c] = v.x;
        y[2 * c + 1] = v.y;
    }
    if (t == 63) y[2 * CH - 1] = 0.f;  // col ncols pad
    float s1l = 0.f, sabl = 0.f;
#pragma unroll
    for (int q = 0; q < 2 * CH; ++q) { s1l += y[q] * y[q]; sabl += fabsf(y[q]); }
    float s1 = wredsum(s1l);
    float sab = wredsum(sabl);
    bool allz = (sab == 0.0f);
    float n = sqrtf(fmaxf(s1 + EPSF, 1e-6f));
    float sh = sinhf(fminf(n, 50.f));
    float fac = sh / n;
    float tq[2 * CH];
    float s2l = 0.f;
#pragma unroll
    for (int q = 0; q < 2 * CH; ++q) { tq[q] = allz ? 0.f : y[q] * fac; s2l += tq[q] * tq[q]; }
    float s2 = wredsum(s2l);
    float first = allz ? 0.f : sqrtf(1.f + s2);
    float dist = arcosh_f(first + EPSF);
    float rs = dist / sqrtf(s2 + EPSF);
    float rq[2 * CH];
    float s3l = 0.f;
#pragma unroll
    for (int q = 0; q < 2 * CH; ++q) { rq[q] = fmaxf(rs * tq[q], 0.f); s3l += rq[q] * rq[q]; }
    float s3 = wredsum(s3l);
    float n2 = sqrtf(fmaxf(s3 + EPSF, 1e-6f));
    float sh2 = sinhf(fminf(n2, 50.f));
    float fac2 = sh2 / n2;
    float uq[2 * CH];
    float s4l = 0.f;
#pragma unroll
    for (int q = 0; q < 2 * CH; ++q) { uq[q] = rq[q] * fac2; s4l += uq[q] * uq[q]; }
    float s4 = wredsum(s4l);
    float first2 = sqrtf(1.f + s4);
    float dist2 = arcosh_f(first2 + EPSF);
    float sc2 = dist2 / sqrtf(s4 + EPSF);
    ushort_t* orow = out + (size_t)i * ldo;
#pragma unroll
    for (int c = 0; c < CH; ++c) {
        ushort2 o;
        o.x = f2bf(sc2 * uq[2 * c]);
        o.y = f2bf(sc2 * uq[2 * c + 1]);
        *reinterpret_cast<ushort2*>(orow + c * 128 + 2 * t) = o;
    }
}

// ---------- mean partials (deterministic, bf16 in) ----------
__global__ __launch_bounds__(384) void k_mean(const char* __restrict__ Rbase,
                                              float* __restrict__ partials, int N, int chunk) {
    int b = blockIdx.x;
    int j = threadIdx.x;
    int lo = b * chunk;
    int hi = lo + chunk; if (hi > N) hi = N;
    float acc = 0.f;
    for (int n = lo; n < hi; ++n)
        acc += bf2f(*reinterpret_cast<const ushort_t*>(Rbase + (size_t)n * 1536 + 2 * j));
    partials[(size_t)b * 384 + j] = acc;
}

// ---------- stage-2 mean reduce: one block per feature j ----------
__global__ __launch_bounds__(256) void k_mred(const float* __restrict__ partials,
                                              float* __restrict__ hm, int nparts, int N) {
    __shared__ float sb[256];
    int j = blockIdx.x, t = threadIdx.x;
    float v = (t < nparts) ? partials[(size_t)t * 384 + j] : 0.f;
    sb[t] = v; __syncthreads();
    for (int st = 128; st > 0; st >>= 1) { if (t < st) sb[t] += sb[t + st]; __syncthreads(); }
    if (t == 0) hm[j] = sb[0] / (float)N;
}

// ---------- classifier head: single wave, parallel loads ----------
__global__ __launch_bounds__(64) void k_head(const float* __restrict__ hm,
                                             const float* __restrict__ Wc,
                                             const float* __restrict__ bc,
                                             float* __restrict__ dout, int ic, int oc) {
    int t = threadIdx.x;
    float h[6];
    float ss = 0.f;
#pragma unroll
    for (int c = 0; c < 6; ++c) {
        int j = t + 64 * c;
        h[c] = (j < ic) ? hm[j] : 0.f;
        ss += h[c] * h[c];
    }
    float ssum = wredsum(ss);
    float dist = arcosh_f(0.0f + EPSF);  // hm[0] (time component) = 0
    float scl = dist / sqrtf(ssum + EPSF);
    float mxv[9];
#pragma unroll
    for (int o = 0; o < 9; ++o) {
        float p = 0.f;
        if (o < oc) {
#pragma unroll
            for (int c = 0; c < 6; ++c) {
                int j = t + 64 * c;
                if (j < ic) p += h[c] * Wc[(size_t)o * ic + j];
            }
        }
        float s = wredsum(p);
        mxv[o] = (o < oc) ? (scl * s + bc[o]) : 0.f;
    }
    if (t == 0) {
        float y[10], tt[10], lt[11], p[11], t3[11];
        float s1 = 0.f, sab = 0.f;
        for (int j = 0; j < 9; ++j) {
            y[j] = (j < oc) ? mxv[j] : 0.f;
            s1 += y[j] * y[j]; sab += fabsf(y[j]);
        }
        bool allz = (sab == 0.f);
        float n = sqrtf(fmaxf(s1 + EPSF, 1e-6f));
        float sh = sinhf(fminf(n, 50.f));
        float s2 = 0.f;
        for (int j = 0; j < oc; ++j) { tt[j] = allz ? 0.f : sh * y[j] / n; s2 += tt[j] * tt[j]; }
        float first = allz ? 0.f : sqrtf(1.f + s2);
        dout[0] = first;
        for (int j = 0; j < oc; ++j) dout[1 + j] = tt[j];
        float dist2 = arcosh_f(first + EPSF);
        float nrm2 = sqrtf(s2 + EPSF);
        lt[0] = 0.f;
        for (int j = 0; j < oc; ++j) lt[1 + j] = dist2 / nrm2 * tt[j];
        float m = lt[0];
        for (int j = 1; j <= oc; ++j) m = fmaxf(m, lt[j]);
        float es = 0.f;
        for (int j = 0; j <= oc; ++j) { p[j] = expf(lt[j] - m); es += p[j]; }
        for (int j = 0; j <= oc; ++j) p[j] /= es;
        p[0] = 0.f;
        float s3 = 0.f;
        for (int j = 1; j <= oc; ++j) s3 += p[j] * p[j];
        float n3 = sqrtf(fmaxf(s3 + EPSF, 1e-6f));
        float sh3 = sinhf(fminf(n3, 50.f));
        float s4 = 0.f;
        for (int j = 1; j <= oc; ++j) { t3[j] = sh3 * p[j] / n3; s4 += t3[j] * t3[j]; }
        dout[1 + oc] = sqrtf(1.f + s4);
        for (int j = 1; j <= oc; ++j) dout[1 + oc + j] = t3[j];
    }
}

extern "C" void kernel_launch(void* const* d_in, const int* in_sizes, int n_in,
                              void* d_out, int out_size, void* d_ws, size_t ws_size,
                              hipStream_t stream) {
    if (n_in < 10) return;
    const float* x   = (const float*)d_in[0];
    const int*   ei  = (const int*)d_in[1];
    const float* W0  = (const float*)d_in[2];
    const float* b0  = (const float*)d_in[3];
    const float* W1  = (const float*)d_in[4];
    const float* b1  = (const float*)d_in[5];
    const float* W2  = (const float*)d_in[6];
    const float* b2  = (const float*)d_in[7];
    const float* Wc  = (const float*)d_in[8];
    const float* bc  = (const float*)d_in[9];
    float* dout = (float*)d_out;

    int N = in_sizes[0] / 128;
    int E = in_sizes[1] / 2;
    int o1 = in_sizes[3];           // 127
    int i1 = in_sizes[2] / o1;      // 127
    int o2 = in_sizes[5];           // 255
    int i2 = in_sizes[4] / o2;      // 127
    int o3 = in_sizes[7];           // 383
    int i3 = in_sizes[6] / o3;      // 255
    int oc = in_sizes[9];           // 9
    int ic = in_sizes[8] / oc;      // 383

    int M_pad = ((N + 127) / 128) * 128;             // 50048
    int Kp1 = ((i1 + 31) / 32) * 32;                 // 128
    int Kp2 = ((i2 + 31) / 32) * 32;                 // 128
    int Kp3 = ((i3 + 31) / 32) * 32;                 // 256
    int Np1 = ((o1 + 127) / 128) * 128;              // 128
    int Np2 = ((o2 + 127) / 128) * 128;              // 256
    int Np3 = ((o3 + 127) / 128) * 128;              // 384

    const int* esrc = ei;
    const int* edst = ei + E;

    char* ws = (char*)d_ws;
    auto alloc = [&](size_t bytes) {
        char* p = ws;
        ws += (bytes + 511) & ~(size_t)511;
        return p;
    };
    ushort_t* Ab     = (ushort_t*)alloc((size_t)M_pad * 256 * 2);  // A (lo half) + xt0 (hi half)
    float*    R      = (float*)alloc((size_t)M_pad * 384 * 4);     // Y buffers / ht (bf16 in-place)
    ushort_t* Wb0    = (ushort_t*)alloc((size_t)Np1 * Kp1 * 2);
    ushort_t* Wb1    = (ushort_t*)alloc((size_t)Np2 * Kp2 * 2);
    ushort_t* Wb2    = (ushort_t*)alloc((size_t)Np3 * Kp3 * 2);
    int*      counts = (int*)alloc((size_t)N * 4);
    int*      row_ptr= (int*)alloc((size_t)(N + 1) * 4);
    int*      cursor = (int*)alloc((size_t)N * 4);
    int*      srcl   = (int*)alloc((size_t)E * 4);
    int*      bsum   = (int*)alloc(4096 * 4);
    int*      bscan  = (int*)alloc(4096 * 4);
    float*    partials = (float*)alloc((size_t)256 * 384 * 4);
    float*    hmbuf  = (float*)alloc(512 * 4);
    (void)ws_size;

    int zb = (N + 255) / 256;
    int NB = (N + 1023) / 1024;
    int eb = (E + 255) / 256;

    // weight conversion (bf16, padded; W0 k-shifted by 1 to absorb tail indexing)
    k_convw<<<dim3((Np1 * Kp1 + 255) / 256), dim3(256), 0, stream>>>(W0, Wb0, o1, i1, Kp1, 1, Np1 * Kp1);
    k_convw<<<dim3((Np2 * Kp2 + 255) / 256), dim3(256), 0, stream>>>(W1, Wb1, o2, i2, Kp2, 0, Np2 * Kp2);
    k_convw<<<dim3((Np3 * Kp3 + 255) / 256), dim3(256), 0, stream>>>(W2, Wb2, o3, i3, Kp3, 0, Np3 * Kp3);
    // 1. log_map_zero(x) -> xt0 bf16
    k_log0<<<dim3(N), dim3(64), 0, stream>>>(x, (char*)Ab, N);
    // 2. CSR build (one edge per thread: max memory-level parallelism)
    k_zero_i<<<dim3(zb), dim3(256), 0, stream>>>(counts, N);
    k_hist<<<dim3(eb), dim3(256), 0, stream>>>(edst, counts, E);
    k_bsum<<<dim3(NB), dim3(256), 0, stream>>>(counts, bsum, N);
    k_bscan<<<dim3(1), dim3(1), 0, stream>>>(bsum, bscan, row_ptr, NB, N);
    k_scan3<<<dim3(NB), dim3(256), 0, stream>>>(counts, bscan, row_ptr, cursor, N);
    k_fill<<<dim3(eb), dim3(256), 0, stream>>>(esrc, edst, cursor, srcl, E);
    // 3. aggregate + exp + fused log -> A (bf16)
    k_agg<<<dim3(N), dim3(64), 0, stream>>>((const char*)Ab, row_ptr, srcl, Ab, N);
    // 4. layer 1
    k_gemm<<<dim3(M_pad / 128, Np1 / 128), dim3(256), 0, stream>>>(Ab, 256, Wb0, Kp1, b0, R, 128, Kp1, o1);
    k_ep<128><<<dim3(N), dim3(64), 0, stream>>>(R, 128, Ab, 256, N);
    // 5. layer 2
    k_gemm<<<dim3(M_pad / 128, Np2 / 128), dim3(256), 0, stream>>>(Ab, 256, Wb1, Kp2, b1, R, 256, Kp2, o2);
    k_ep<256><<<dim3(N), dim3(64), 0, stream>>>(R, 256, Ab, 256, N);
    // 6. layer 3
    k_gemm<<<dim3(M_pad / 128, Np3 / 128), dim3(256), 0, stream>>>(Ab, 256, Wb2, Kp3, b2, R, 384, Kp3, o3);
    k_ep<384><<<dim3(N), dim3(64), 0, stream>>>(R, 384, (ushort_t*)R, 768, N);  // ht bf16 in-place
    // 7. deterministic mean: stage 1 partials, stage 2 per-feature tree
    int chunk = (N + 255) / 256;
    k_mean<<<dim3(256), dim3(384), 0, stream>>>((const char*)R, partials, N, chunk);
    k_mred<<<dim3(383), dim3(256), 0, stream>>>(partials, hmbuf, 256, N);
    // 8. classifier head (single wave, parallel loads)
    k_head<<<dim3(1), dim3(64), 0, stream>>>(hmbuf, Wc, bc, dout, ic, oc);
}

// Round 5
// 392.654 us; speedup vs baseline: 3.2441x; 1.0571x over previous
//
#include <hip/hip_runtime.h>
#include <math.h>

#define EPSF 1e-7f

typedef unsigned short ushort_t;
typedef __attribute__((ext_vector_type(8))) short bf16x8;
typedef __attribute__((ext_vector_type(4))) float f32x4;

__device__ __forceinline__ float arcosh_f(float x) {
    x = fmaxf(x, 1.0f + EPSF);
    return logf(x + sqrtf(x * x - 1.0f));
}

__device__ __forceinline__ unsigned short f2bf(float f) {
    union { float f; unsigned u; } c; c.f = f;
    unsigned r = c.u + 0x7FFFu + ((c.u >> 16) & 1u);
    return (unsigned short)(r >> 16);
}
__device__ __forceinline__ float bf2f(unsigned short u) {
    union { unsigned u; float f; } c; c.u = ((unsigned)u) << 16;
    return c.f;
}

__device__ __forceinline__ float wredsum(float v) {
#pragma unroll
    for (int off = 32; off; off >>= 1) v += __shfl_xor(v, off, 64);
    return v;
}

__device__ __forceinline__ void llds16(const void* g, void* l) {
    __builtin_amdgcn_global_load_lds((const __attribute__((address_space(1))) unsigned int*)g,
                                     (__attribute__((address_space(3))) unsigned int*)l,
                                     16, 0, 0);
}

// ---------- K1: xt0 = log_map_zero(x) -> bf16, stored in upper half of Abuf rows ----------
__global__ __launch_bounds__(64) void k_log0(const float* __restrict__ x,
                                             char* __restrict__ Abase, int N) {
    int i = blockIdx.x, t = threadIdx.x;
    float2 v = *reinterpret_cast<const float2*>(x + (size_t)i * 128 + 2 * t);
    float y0 = __shfl(v.x, 0, 64);
    float a0 = (t == 0) ? 0.f : v.x;
    float s = wredsum(a0 * a0 + v.y * v.y);
    float dist = arcosh_f(y0 + EPSF);
    float scl = dist / sqrtf(s + EPSF);
    ushort2 o;
    o.x = f2bf(scl * a0);
    o.y = f2bf(scl * v.y);
    *reinterpret_cast<ushort2*>(Abase + (size_t)i * 512 + 256 + 4 * t) = o;
}

// ---------- CSR build ----------
__global__ void k_zero_i(int* __restrict__ p, int n) {
    int i = blockIdx.x * blockDim.x + threadIdx.x;
    if (i < n) p[i] = 0;
}
__global__ void k_hist(const int* __restrict__ dst, int* __restrict__ counts, int E) {
    int e = blockIdx.x * blockDim.x + threadIdx.x;
    if (e < E) atomicAdd(&counts[dst[e]], 1);
}
__global__ __launch_bounds__(256) void k_bsum(const int* __restrict__ counts,
                                              int* __restrict__ bsum, int N) {
    __shared__ int ib[256];
    int b = blockIdx.x, t = threadIdx.x;
    int base = b * 1024 + t * 4;
    int s = 0;
    for (int i = 0; i < 4; ++i) { int g = base + i; if (g < N) s += counts[g]; }
    ib[t] = s; __syncthreads();
    for (int st = 128; st > 0; st >>= 1) { if (t < st) ib[t] += ib[t + st]; __syncthreads(); }
    if (t == 0) bsum[b] = ib[0];
}
__global__ void k_bscan(const int* __restrict__ bsum, int* __restrict__ bscan,
                        int* __restrict__ row_ptr, int NB, int N) {
    if (blockIdx.x == 0 && threadIdx.x == 0) {
        int run = 0;
        for (int b = 0; b < NB; ++b) { bscan[b] = run; run += bsum[b]; }
        row_ptr[N] = run;
    }
}
__global__ __launch_bounds__(256) void k_scan3(const int* __restrict__ counts,
                                               const int* __restrict__ bscan,
                                               int* __restrict__ row_ptr,
                                               int* __restrict__ cursor, int N) {
    __shared__ int ib[256];
    int b = blockIdx.x, t = threadIdx.x;
    int base = b * 1024 + t * 4;
    int c[4]; int ts = 0;
    for (int i = 0; i < 4; ++i) { int g = base + i; c[i] = (g < N) ? counts[g] : 0; ts += c[i]; }
    ib[t] = ts; __syncthreads();
    for (int st = 1; st < 256; st <<= 1) {
        int v = (t >= st) ? ib[t - st] : 0;
        __syncthreads();
        ib[t] += v;
        __syncthreads();
    }
    int run = ib[t] - ts + bscan[b];
    for (int i = 0; i < 4; ++i) {
        int g = base + i;
        if (g < N) { row_ptr[g] = run; cursor[g] = run; }
        run += c[i];
    }
}
__global__ void k_fill(const int* __restrict__ src, const int* __restrict__ dst,
                       int* __restrict__ cursor, int* __restrict__ out_src, int E) {
    int e = blockIdx.x * blockDim.x + threadIdx.x;
    if (e < E) {
        int pos = atomicAdd(&cursor[dst[e]], 1);
        out_src[pos] = src[e];
    }
}

// ---------- K3: agg (4-way unrolled gather) + exp_map + fused log_map -> A1 ----------
__global__ __launch_bounds__(64) void k_agg(const char* __restrict__ Abase,
                                            const int* __restrict__ row_ptr,
                                            const int* __restrict__ srcl,
                                            ushort_t* __restrict__ Ab, int N) {
    int i = blockIdx.x, t = threadIdx.x;
    const char* base = Abase + 256 + 4 * t;
    ushort2 sv = *reinterpret_cast<const ushort2*>(base + (size_t)i * 512);
    float a0 = bf2f(sv.x), a1 = bf2f(sv.y);
    float b0 = 0.f, b1 = 0.f, c0 = 0.f, c1 = 0.f, d0 = 0.f, d1 = 0.f;
    int b = row_ptr[i], e = row_ptr[i + 1];
    int k = b;
    for (; k + 4 <= e; k += 4) {
        int s0 = srcl[k], s1 = srcl[k + 1], s2 = srcl[k + 2], s3 = srcl[k + 3];
        ushort2 v0 = *reinterpret_cast<const ushort2*>(base + (size_t)s0 * 512);
        ushort2 v1 = *reinterpret_cast<const ushort2*>(base + (size_t)s1 * 512);
        ushort2 v2 = *reinterpret_cast<const ushort2*>(base + (size_t)s2 * 512);
        ushort2 v3 = *reinterpret_cast<const ushort2*>(base + (size_t)s3 * 512);
        a0 += bf2f(v0.x); a1 += bf2f(v0.y);
        b0 += bf2f(v1.x); b1 += bf2f(v1.y);
        c0 += bf2f(v2.x); c1 += bf2f(v2.y);
        d0 += bf2f(v3.x); d1 += bf2f(v3.y);
    }
    for (; k < e; ++k) {
        int s = srcl[k];
        ushort2 v = *reinterpret_cast<const ushort2*>(base + (size_t)s * 512);
        a0 += bf2f(v.x); a1 += bf2f(v.y);
    }
    float u0 = (a0 + b0) + (c0 + d0);
    float u1 = (a1 + b1) + (c1 + d1);
    if (t == 0) u0 = 0.f;
    float s1 = wredsum(u0 * u0 + u1 * u1);
    float n = sqrtf(fmaxf(s1 + EPSF, 1e-6f));
    float sh = sinhf(fminf(n, 50.f));
    float t0 = sh * u0 / n, t1 = sh * u1 / n;
    float s2 = wredsum(t0 * t0 + t1 * t1);
    float first = sqrtf(1.f + s2);
    float dist = arcosh_f(first + EPSF);
    float scl = dist / sqrtf(s2 + EPSF);
    ushort2 o;
    o.x = f2bf(scl * t0);
    o.y = f2bf(scl * t1);
    *reinterpret_cast<ushort2*>(Ab + (size_t)i * 256 + 2 * t) = o;
}

// ---------- W conversion (all 3 layers, one launch) ----------
__global__ void k_convw3(const float* __restrict__ W0, const float* __restrict__ W1,
                         const float* __restrict__ W2,
                         ushort_t* __restrict__ Wb0, ushort_t* __restrict__ Wb1,
                         ushort_t* __restrict__ Wb2,
                         int o1, int i1, int Kp1, int o2, int i2, int Kp2,
                         int o3, int i3, int Kp3, int t1, int t2, int t3) {
    int idx = blockIdx.x * blockDim.x + threadIdx.x;
    const float* W; ushort_t* Wb; int ncols, K, Kp, shift;
    if (idx < t1) { W = W0; Wb = Wb0; ncols = o1; K = i1; Kp = Kp1; shift = 1; }
    else if (idx < t1 + t2) { idx -= t1; W = W1; Wb = Wb1; ncols = o2; K = i2; Kp = Kp2; shift = 0; }
    else if (idx < t1 + t2 + t3) { idx -= t1 + t2; W = W2; Wb = Wb2; ncols = o3; K = i3; Kp = Kp3; shift = 0; }
    else return;
    int o = idx / Kp, kk = idx - o * Kp;
    int ks = kk - shift;
    float v = 0.f;
    if (o < ncols && ks >= 0 && ks < K) v = W[(size_t)o * K + ks];
    Wb[idx] = f2bf(v);
}

// ---------- MFMA bf16 GEMM: Yb[M x ncols] = A @ W^T + bias, bf16 output ----------
__global__ __launch_bounds__(256) void k_gemm(const ushort_t* __restrict__ Ab, int lda,
                                              const ushort_t* __restrict__ Wb, int ldw,
                                              const float* __restrict__ bias,
                                              ushort_t* __restrict__ Yb, int ldy,
                                              int Kp, int ncols) {
    __shared__ ushort_t As[128 * 32];
    __shared__ ushort_t Bs[128 * 32];
    int tid = threadIdx.x;
    int lane = tid & 63, wv = tid >> 6;
    int bm = blockIdx.x * 128, bn = blockIdx.y * 128;
    int r = lane & 15, g4 = lane >> 4;
    int wr = (wv >> 1) * 64, wc = (wv & 1) * 64;

    f32x4 acc[4][4] = {};
    for (int k0 = 0; k0 < Kp; k0 += 32) {
#pragma unroll
        for (int ci = 0; ci < 2; ++ci) {
            int L = (wv * 2 + ci) * 1024 + lane * 16;
            int row = L >> 6, kb = L & 63;
            const char* ga = (const char*)Ab + ((size_t)(bm + row) * lda + k0) * 2 + kb;
            llds16(ga, (char*)As + (wv * 2 + ci) * 1024);
            const char* gb = (const char*)Wb + ((size_t)(bn + row) * ldw + k0) * 2 + kb;
            llds16(gb, (char*)Bs + (wv * 2 + ci) * 1024);
        }
        __syncthreads();
        bf16x8 af[4], bfr[4];
#pragma unroll
        for (int m = 0; m < 4; ++m)
            af[m] = *reinterpret_cast<const bf16x8*>((const char*)As + (wr + m * 16 + r) * 64 + g4 * 16);
#pragma unroll
        for (int n2 = 0; n2 < 4; ++n2)
            bfr[n2] = *reinterpret_cast<const bf16x8*>((const char*)Bs + (wc + n2 * 16 + r) * 64 + g4 * 16);
#pragma unroll
        for (int m = 0; m < 4; ++m)
#pragma unroll
            for (int n2 = 0; n2 < 4; ++n2)
                acc[m][n2] = __builtin_amdgcn_mfma_f32_16x16x32_bf16(af[m], bfr[n2], acc[m][n2], 0, 0, 0);
        __syncthreads();
    }
#pragma unroll
    for (int n2 = 0; n2 < 4; ++n2) {
        int col = bn + wc + n2 * 16 + r;
        if (col >= ncols) continue;
        float bv = bias[col];
#pragma unroll
        for (int m = 0; m < 4; ++m) {
#pragma unroll
            for (int j = 0; j < 4; ++j) {
                int row = bm + wr + m * 16 + g4 * 4 + j;
                Yb[(size_t)row * ldy + col] = f2bf(acc[m][n2][j] + bv);
            }
        }
    }
}

// ---------- Epilogue: exp_map(+allzero), log, relu, exp_map, fused next log. bf16 in/out ----------
template <int NCP>
__global__ __launch_bounds__(64) void k_ep(const ushort_t* __restrict__ Y, int ldy,
                                           ushort_t* __restrict__ out, int ldo, int N) {
    constexpr int CH = NCP / 128;
    int i = blockIdx.x, t = threadIdx.x;
    const ushort_t* yr = Y + (size_t)i * ldy;
    float y[2 * CH];
#pragma unroll
    for (int c = 0; c < CH; ++c) {
        ushort2 v = *reinterpret_cast<const ushort2*>(yr + c * 128 + 2 * t);
        y[2 * c] = bf2f(v.x);
        y[2 * c + 1] = bf2f(v.y);
    }
    if (t == 63) y[2 * CH - 1] = 0.f;  // pad column
    float s1l = 0.f, sabl = 0.f;
#pragma unroll
    for (int q = 0; q < 2 * CH; ++q) { s1l += y[q] * y[q]; sabl += fabsf(y[q]); }
    float s1 = wredsum(s1l);
    float sab = wredsum(sabl);
    bool allz = (sab == 0.0f);
    float n = sqrtf(fmaxf(s1 + EPSF, 1e-6f));
    float sh = sinhf(fminf(n, 50.f));
    float fac = sh / n;
    float tq[2 * CH];
    float s2l = 0.f;
#pragma unroll
    for (int q = 0; q < 2 * CH; ++q) { tq[q] = allz ? 0.f : y[q] * fac; s2l += tq[q] * tq[q]; }
    float s2 = wredsum(s2l);
    float first = allz ? 0.f : sqrtf(1.f + s2);
    float dist = arcosh_f(first + EPSF);
    float rs = dist / sqrtf(s2 + EPSF);
    float rq[2 * CH];
    float s3l = 0.f;
#pragma unroll
    for (int q = 0; q < 2 * CH; ++q) { rq[q] = fmaxf(rs * tq[q], 0.f); s3l += rq[q] * rq[q]; }
    float s3 = wredsum(s3l);
    float n2 = sqrtf(fmaxf(s3 + EPSF, 1e-6f));
    float sh2 = sinhf(fminf(n2, 50.f));
    float fac2 = sh2 / n2;
    float uq[2 * CH];
    float s4l = 0.f;
#pragma unroll
    for (int q = 0; q < 2 * CH; ++q) { uq[q] = rq[q] * fac2; s4l += uq[q] * uq[q]; }
    float s4 = wredsum(s4l);
    float first2 = sqrtf(1.f + s4);
    float dist2 = arcosh_f(first2 + EPSF);
    float sc2 = dist2 / sqrtf(s4 + EPSF);
    ushort_t* orow = out + (size_t)i * ldo;
#pragma unroll
    for (int c = 0; c < CH; ++c) {
        ushort2 o;
        o.x = f2bf(sc2 * uq[2 * c]);
        o.y = f2bf(sc2 * uq[2 * c + 1]);
        *reinterpret_cast<ushort2*>(orow + c * 128 + 2 * t) = o;
    }
}

// ---------- mean partials (deterministic, bf16 in, 768B row pitch) ----------
__global__ __launch_bounds__(384) void k_mean(const char* __restrict__ Rbase,
                                              float* __restrict__ partials, int N, int chunk) {
    int b = blockIdx.x;
    int j = threadIdx.x;
    int lo = b * chunk;
    int hi = lo + chunk; if (hi > N) hi = N;
    float acc = 0.f;
    for (int n = lo; n < hi; ++n)
        acc += bf2f(*reinterpret_cast<const ushort_t*>(Rbase + (size_t)n * 768 + 2 * j));
    partials[(size_t)b * 384 + j] = acc;
}

// ---------- stage-2 mean reduce: one block per feature j ----------
__global__ __launch_bounds__(256) void k_mred(const float* __restrict__ partials,
                                              float* __restrict__ hm, int nparts, int N) {
    __shared__ float sb[256];
    int j = blockIdx.x, t = threadIdx.x;
    float v = (t < nparts) ? partials[(size_t)t * 384 + j] : 0.f;
    sb[t] = v; __syncthreads();
    for (int st = 128; st > 0; st >>= 1) { if (t < st) sb[t] += sb[t + st]; __syncthreads(); }
    if (t == 0) hm[j] = sb[0] / (float)N;
}

// ---------- classifier head: single wave, parallel loads ----------
__global__ __launch_bounds__(64) void k_head(const float* __restrict__ hm,
                                             const float* __restrict__ Wc,
                                             const float* __restrict__ bc,
                                             float* __restrict__ dout, int ic, int oc) {
    int t = threadIdx.x;
    float h[6];
    float ss = 0.f;
#pragma unroll
    for (int c = 0; c < 6; ++c) {
        int j = t + 64 * c;
        h[c] = (j < ic) ? hm[j] : 0.f;
        ss += h[c] * h[c];
    }
    float ssum = wredsum(ss);
    float dist = arcosh_f(0.0f + EPSF);  // hm time component = 0
    float scl = dist / sqrtf(ssum + EPSF);
    float mxv[9];
#pragma unroll
    for (int o = 0; o < 9; ++o) {
        float p = 0.f;
        if (o < oc) {
#pragma unroll
            for (int c = 0; c < 6; ++c) {
                int j = t + 64 * c;
                if (j < ic) p += h[c] * Wc[(size_t)o * ic + j];
            }
        }
        float s = wredsum(p);
        mxv[o] = (o < oc) ? (scl * s + bc[o]) : 0.f;
    }
    if (t == 0) {
        float y[10], tt[10], lt[11], p[11], t3[11];
        float s1 = 0.f, sab = 0.f;
        for (int j = 0; j < 9; ++j) {
            y[j] = (j < oc) ? mxv[j] : 0.f;
            s1 += y[j] * y[j]; sab += fabsf(y[j]);
        }
        bool allz = (sab == 0.f);
        float n = sqrtf(fmaxf(s1 + EPSF, 1e-6f));
        float sh = sinhf(fminf(n, 50.f));
        float s2 = 0.f;
        for (int j = 0; j < oc; ++j) { tt[j] = allz ? 0.f : sh * y[j] / n; s2 += tt[j] * tt[j]; }
        float first = allz ? 0.f : sqrtf(1.f + s2);
        dout[0] = first;
        for (int j = 0; j < oc; ++j) dout[1 + j] = tt[j];
        float dist2 = arcosh_f(first + EPSF);
        float nrm2 = sqrtf(s2 + EPSF);
        lt[0] = 0.f;
        for (int j = 0; j < oc; ++j) lt[1 + j] = dist2 / nrm2 * tt[j];
        float m = lt[0];
        for (int j = 1; j <= oc; ++j) m = fmaxf(m, lt[j]);
        float es = 0.f;
        for (int j = 0; j <= oc; ++j) { p[j] = expf(lt[j] - m); es += p[j]; }
        for (int j = 0; j <= oc; ++j) p[j] /= es;
        p[0] = 0.f;
        float s3 = 0.f;
        for (int j = 1; j <= oc; ++j) s3 += p[j] * p[j];
        float n3 = sqrtf(fmaxf(s3 + EPSF, 1e-6f));
        float sh3 = sinhf(fminf(n3, 50.f));
        float s4 = 0.f;
        for (int j = 1; j <= oc; ++j) { t3[j] = sh3 * p[j] / n3; s4 += t3[j] * t3[j]; }
        dout[1 + oc] = sqrtf(1.f + s4);
        for (int j = 1; j <= oc; ++j) dout[1 + oc + j] = t3[j];
    }
}

extern "C" void kernel_launch(void* const* d_in, const int* in_sizes, int n_in,
                              void* d_out, int out_size, void* d_ws, size_t ws_size,
                              hipStream_t stream) {
    if (n_in < 10) return;
    const float* x   = (const float*)d_in[0];
    const int*   ei  = (const int*)d_in[1];
    const float* W0  = (const float*)d_in[2];
    const float* b0  = (const float*)d_in[3];
    const float* W1  = (const float*)d_in[4];
    const float* b1  = (const float*)d_in[5];
    const float* W2  = (const float*)d_in[6];
    const float* b2  = (const float*)d_in[7];
    const float* Wc  = (const float*)d_in[8];
    const float* bc  = (const float*)d_in[9];
    float* dout = (float*)d_out;

    int N = in_sizes[0] / 128;
    int E = in_sizes[1] / 2;
    int o1 = in_sizes[3];           // 127
    int i1 = in_sizes[2] / o1;      // 127
    int o2 = in_sizes[5];           // 255
    int i2 = in_sizes[4] / o2;      // 127
    int o3 = in_sizes[7];           // 383
    int i3 = in_sizes[6] / o3;      // 255
    int oc = in_sizes[9];           // 9
    int ic = in_sizes[8] / oc;      // 383

    int M_pad = ((N + 127) / 128) * 128;             // 50048
    int Kp1 = ((i1 + 31) / 32) * 32;                 // 128
    int Kp2 = ((i2 + 31) / 32) * 32;                 // 128
    int Kp3 = ((i3 + 31) / 32) * 32;                 // 256
    int Np1 = ((o1 + 127) / 128) * 128;              // 128
    int Np2 = ((o2 + 127) / 128) * 128;              // 256
    int Np3 = ((o3 + 127) / 128) * 128;              // 384

    const int* esrc = ei;
    const int* edst = ei + E;

    char* ws = (char*)d_ws;
    auto alloc = [&](size_t bytes) {
        char* p = ws;
        ws += (bytes + 511) & ~(size_t)511;
        return p;
    };
    ushort_t* Ab     = (ushort_t*)alloc((size_t)M_pad * 256 * 2);  // A (lo half) + xt0 (hi half)
    ushort_t* R      = (ushort_t*)alloc((size_t)M_pad * 384 * 2);  // Y / ht (bf16)
    ushort_t* Wb0    = (ushort_t*)alloc((size_t)Np1 * Kp1 * 2);
    ushort_t* Wb1    = (ushort_t*)alloc((size_t)Np2 * Kp2 * 2);
    ushort_t* Wb2    = (ushort_t*)alloc((size_t)Np3 * Kp3 * 2);
    int*      counts = (int*)alloc((size_t)N * 4);
    int*      row_ptr= (int*)alloc((size_t)(N + 1) * 4);
    int*      cursor = (int*)alloc((size_t)N * 4);
    int*      srcl   = (int*)alloc((size_t)E * 4);
    int*      bsum   = (int*)alloc(4096 * 4);
    int*      bscan  = (int*)alloc(4096 * 4);
    float*    partials = (float*)alloc((size_t)256 * 384 * 4);
    float*    hmbuf  = (float*)alloc(512 * 4);
    (void)ws_size;

    int zb = (N + 255) / 256;
    int NB = (N + 1023) / 1024;
    int eb = (E + 255) / 256;

    int t1 = Np1 * Kp1, t2 = Np2 * Kp2, t3 = Np3 * Kp3;
    k_convw3<<<dim3((t1 + t2 + t3 + 255) / 256), dim3(256), 0, stream>>>(
        W0, W1, W2, Wb0, Wb1, Wb2, o1, i1, Kp1, o2, i2, Kp2, o3, i3, Kp3, t1, t2, t3);
    // 1. log_map_zero(x) -> xt0 bf16
    k_log0<<<dim3(N), dim3(64), 0, stream>>>(x, (char*)Ab, N);
    // 2. CSR build (one edge per thread)
    k_zero_i<<<dim3(zb), dim3(256), 0, stream>>>(counts, N);
    k_hist<<<dim3(eb), dim3(256), 0, stream>>>(edst, counts, E);
    k_bsum<<<dim3(NB), dim3(256), 0, stream>>>(counts, bsum, N);
    k_bscan<<<dim3(1), dim3(1), 0, stream>>>(bsum, bscan, row_ptr, NB, N);
    k_scan3<<<dim3(NB), dim3(256), 0, stream>>>(counts, bscan, row_ptr, cursor, N);
    k_fill<<<dim3(eb), dim3(256), 0, stream>>>(esrc, edst, cursor, srcl, E);
    // 3. aggregate (unrolled gather) + exp + fused log -> A (bf16)
    k_agg<<<dim3(N), dim3(64), 0, stream>>>((const char*)Ab, row_ptr, srcl, Ab, N);
    // 4. layer 1
    k_gemm<<<dim3(M_pad / 128, Np1 / 128), dim3(256), 0, stream>>>(Ab, 256, Wb0, Kp1, b0, R, 128, Kp1, o1);
    k_ep<128><<<dim3(N), dim3(64), 0, stream>>>(R, 128, Ab, 256, N);
    // 5. layer 2
    k_gemm<<<dim3(M_pad / 128, Np2 / 128), dim3(256), 0, stream>>>(Ab, 256, Wb1, Kp2, b1, R, 256, Kp2, o2);
    k_ep<256><<<dim3(N), dim3(64), 0, stream>>>(R, 256, Ab, 256, N);
    // 6. layer 3
    k_gemm<<<dim3(M_pad / 128, Np3 / 128), dim3(256), 0, stream>>>(Ab, 256, Wb2, Kp3, b2, R, 384, Kp3, o3);
    k_ep<384><<<dim3(N), dim3(64), 0, stream>>>(R, 384, R, 384, N);  // ht bf16 in-place
    // 7. deterministic mean: stage 1 partials, stage 2 per-feature tree
    int chunk = (N + 255) / 256;
    k_mean<<<dim3(256), dim3(384), 0, stream>>>((const char*)R, partials, N, chunk);
    k_mred<<<dim3(383), dim3(256), 0, stream>>>(partials, hmbuf, 256, N);
    // 8. classifier head (single wave, parallel loads)
    k_head<<<dim3(1), dim3(64), 0, stream>>>(hmbuf, Wc, bc, dout, ic, oc);
}

// Round 6
// 352.446 us; speedup vs baseline: 3.6142x; 1.1141x over previous
//
#include <hip/hip_runtime.h>
#include <math.h>

#define EPSF 1e-7f

typedef unsigned short ushort_t;
typedef __attribute__((ext_vector_type(8))) short bf16x8;
typedef __attribute__((ext_vector_type(4))) float f32x4;

__device__ __forceinline__ float arcosh_f(float x) {
    x = fmaxf(x, 1.0f + EPSF);
    return logf(x + sqrtf(x * x - 1.0f));
}

__device__ __forceinline__ unsigned short f2bf(float f) {
    union { float f; unsigned u; } c; c.f = f;
    unsigned r = c.u + 0x7FFFu + ((c.u >> 16) & 1u);
    return (unsigned short)(r >> 16);
}
__device__ __forceinline__ float bf2f(unsigned short u) {
    union { unsigned u; float f; } c; c.u = ((unsigned)u) << 16;
    return c.f;
}

__device__ __forceinline__ float wredsum(float v) {
#pragma unroll
    for (int off = 32; off; off >>= 1) v += __shfl_xor(v, off, 64);
    return v;
}

__device__ __forceinline__ void llds16(const void* g, void* l) {
    __builtin_amdgcn_global_load_lds((const __attribute__((address_space(1))) unsigned int*)g,
                                     (__attribute__((address_space(3))) unsigned int*)l,
                                     16, 0, 0);
}

// ---------- K1: xt0 = log_map_zero(x) -> bf16, stored in upper half of Abuf rows ----------
__global__ __launch_bounds__(64) void k_log0(const float* __restrict__ x,
                                             char* __restrict__ Abase, int N) {
    int i = blockIdx.x, t = threadIdx.x;
    float2 v = *reinterpret_cast<const float2*>(x + (size_t)i * 128 + 2 * t);
    float y0 = __shfl(v.x, 0, 64);
    float a0 = (t == 0) ? 0.f : v.x;
    float s = wredsum(a0 * a0 + v.y * v.y);
    float dist = arcosh_f(y0 + EPSF);
    float scl = dist / sqrtf(s + EPSF);
    ushort2 o;
    o.x = f2bf(scl * a0);
    o.y = f2bf(scl * v.y);
    *reinterpret_cast<ushort2*>(Abase + (size_t)i * 512 + 256 + 4 * t) = o;
}

// ---------- CSR build ----------
__global__ void k_zero_i(int* __restrict__ p, int n) {
    int i = blockIdx.x * blockDim.x + threadIdx.x;
    if (i < n) p[i] = 0;
}
__global__ void k_hist(const int* __restrict__ dst, int* __restrict__ counts, int E) {
    int e = blockIdx.x * blockDim.x + threadIdx.x;
    if (e < E) atomicAdd(&counts[dst[e]], 1);
}
__global__ __launch_bounds__(256) void k_bsum(const int* __restrict__ counts,
                                              int* __restrict__ bsum, int N) {
    __shared__ int ib[256];
    int b = blockIdx.x, t = threadIdx.x;
    int base = b * 1024 + t * 4;
    int s = 0;
    for (int i = 0; i < 4; ++i) { int g = base + i; if (g < N) s += counts[g]; }
    ib[t] = s; __syncthreads();
    for (int st = 128; st > 0; st >>= 1) { if (t < st) ib[t] += ib[t + st]; __syncthreads(); }
    if (t == 0) bsum[b] = ib[0];
}
__global__ void k_bscan(const int* __restrict__ bsum, int* __restrict__ bscan,
                        int* __restrict__ row_ptr, int NB, int N) {
    if (blockIdx.x == 0 && threadIdx.x == 0) {
        int run = 0;
        for (int b = 0; b < NB; ++b) { bscan[b] = run; run += bsum[b]; }
        row_ptr[N] = run;
    }
}
__global__ __launch_bounds__(256) void k_scan3(const int* __restrict__ counts,
                                               const int* __restrict__ bscan,
                                               int* __restrict__ row_ptr,
                                               int* __restrict__ cursor, int N) {
    __shared__ int ib[256];
    int b = blockIdx.x, t = threadIdx.x;
    int base = b * 1024 + t * 4;
    int c[4]; int ts = 0;
    for (int i = 0; i < 4; ++i) { int g = base + i; c[i] = (g < N) ? counts[g] : 0; ts += c[i]; }
    ib[t] = ts; __syncthreads();
    for (int st = 1; st < 256; st <<= 1) {
        int v = (t >= st) ? ib[t - st] : 0;
        __syncthreads();
        ib[t] += v;
        __syncthreads();
    }
    int run = ib[t] - ts + bscan[b];
    for (int i = 0; i < 4; ++i) {
        int g = base + i;
        if (g < N) { row_ptr[g] = run; cursor[g] = run; }
        run += c[i];
    }
}
__global__ void k_fill(const int* __restrict__ src, const int* __restrict__ dst,
                       int* __restrict__ cursor, int* __restrict__ out_src, int E) {
    int e = blockIdx.x * blockDim.x + threadIdx.x;
    if (e < E) {
        int pos = atomicAdd(&cursor[dst[e]], 1);
        out_src[pos] = src[e];
    }
}

// ---------- K3: agg (4-way unrolled gather) + exp_map + fused log_map -> A1 ----------
__global__ __launch_bounds__(64) void k_agg(const char* __restrict__ Abase,
                                            const int* __restrict__ row_ptr,
                                            const int* __restrict__ srcl,
                                            ushort_t* __restrict__ Ab, int N) {
    int i = blockIdx.x, t = threadIdx.x;
    const char* base = Abase + 256 + 4 * t;
    ushort2 sv = *reinterpret_cast<const ushort2*>(base + (size_t)i * 512);
    float a0 = bf2f(sv.x), a1 = bf2f(sv.y);
    float b0 = 0.f, b1 = 0.f, c0 = 0.f, c1 = 0.f, d0 = 0.f, d1 = 0.f;
    int b = row_ptr[i], e = row_ptr[i + 1];
    int k = b;
    for (; k + 4 <= e; k += 4) {
        int s0 = srcl[k], s1 = srcl[k + 1], s2 = srcl[k + 2], s3 = srcl[k + 3];
        ushort2 v0 = *reinterpret_cast<const ushort2*>(base + (size_t)s0 * 512);
        ushort2 v1 = *reinterpret_cast<const ushort2*>(base + (size_t)s1 * 512);
        ushort2 v2 = *reinterpret_cast<const ushort2*>(base + (size_t)s2 * 512);
        ushort2 v3 = *reinterpret_cast<const ushort2*>(base + (size_t)s3 * 512);
        a0 += bf2f(v0.x); a1 += bf2f(v0.y);
        b0 += bf2f(v1.x); b1 += bf2f(v1.y);
        c0 += bf2f(v2.x); c1 += bf2f(v2.y);
        d0 += bf2f(v3.x); d1 += bf2f(v3.y);
    }
    for (; k < e; ++k) {
        int s = srcl[k];
        ushort2 v = *reinterpret_cast<const ushort2*>(base + (size_t)s * 512);
        a0 += bf2f(v.x); a1 += bf2f(v.y);
    }
    float u0 = (a0 + b0) + (c0 + d0);
    float u1 = (a1 + b1) + (c1 + d1);
    if (t == 0) u0 = 0.f;
    float s1 = wredsum(u0 * u0 + u1 * u1);
    float n = sqrtf(fmaxf(s1 + EPSF, 1e-6f));
    float sh = sinhf(fminf(n, 50.f));
    float t0 = sh * u0 / n, t1 = sh * u1 / n;
    float s2 = wredsum(t0 * t0 + t1 * t1);
    float first = sqrtf(1.f + s2);
    float dist = arcosh_f(first + EPSF);
    float scl = dist / sqrtf(s2 + EPSF);
    ushort2 o;
    o.x = f2bf(scl * t0);
    o.y = f2bf(scl * t1);
    *reinterpret_cast<ushort2*>(Ab + (size_t)i * 256 + 2 * t) = o;
}

// ---------- W conversion (all 3 layers, one launch) ----------
__global__ void k_convw3(const float* __restrict__ W0, const float* __restrict__ W1,
                         const float* __restrict__ W2,
                         ushort_t* __restrict__ Wb0, ushort_t* __restrict__ Wb1,
                         ushort_t* __restrict__ Wb2,
                         int o1, int i1, int Kp1, int o2, int i2, int Kp2,
                         int o3, int i3, int Kp3, int t1, int t2, int t3) {
    int idx = blockIdx.x * blockDim.x + threadIdx.x;
    const float* W; ushort_t* Wb; int ncols, K, Kp, shift;
    if (idx < t1) { W = W0; Wb = Wb0; ncols = o1; K = i1; Kp = Kp1; shift = 1; }
    else if (idx < t1 + t2) { idx -= t1; W = W1; Wb = Wb1; ncols = o2; K = i2; Kp = Kp2; shift = 0; }
    else if (idx < t1 + t2 + t3) { idx -= t1 + t2; W = W2; Wb = Wb2; ncols = o3; K = i3; Kp = Kp3; shift = 0; }
    else return;
    int o = idx / Kp, kk = idx - o * Kp;
    int ks = kk - shift;
    float v = 0.f;
    if (o < ncols && ks >= 0 && ks < K) v = W[(size_t)o * K + ks];
    Wb[idx] = f2bf(v);
}

// ---------- MFMA bf16 GEMM: Yb[M x ncols] = A @ W^T + bias, bf16 output ----------
__global__ __launch_bounds__(256) void k_gemm(const ushort_t* __restrict__ Ab, int lda,
                                              const ushort_t* __restrict__ Wb, int ldw,
                                              const float* __restrict__ bias,
                                              ushort_t* __restrict__ Yb, int ldy,
                                              int Kp, int ncols) {
    __shared__ ushort_t As[128 * 32];
    __shared__ ushort_t Bs[128 * 32];
    int tid = threadIdx.x;
    int lane = tid & 63, wv = tid >> 6;
    int bm = blockIdx.x * 128, bn = blockIdx.y * 128;
    int r = lane & 15, g4 = lane >> 4;
    int wr = (wv >> 1) * 64, wc = (wv & 1) * 64;

    f32x4 acc[4][4] = {};
    for (int k0 = 0; k0 < Kp; k0 += 32) {
#pragma unroll
        for (int ci = 0; ci < 2; ++ci) {
            int L = (wv * 2 + ci) * 1024 + lane * 16;
            int row = L >> 6, kb = L & 63;
            const char* ga = (const char*)Ab + ((size_t)(bm + row) * lda + k0) * 2 + kb;
            llds16(ga, (char*)As + (wv * 2 + ci) * 1024);
            const char* gb = (const char*)Wb + ((size_t)(bn + row) * ldw + k0) * 2 + kb;
            llds16(gb, (char*)Bs + (wv * 2 + ci) * 1024);
        }
        __syncthreads();
        bf16x8 af[4], bfr[4];
#pragma unroll
        for (int m = 0; m < 4; ++m)
            af[m] = *reinterpret_cast<const bf16x8*>((const char*)As + (wr + m * 16 + r) * 64 + g4 * 16);
#pragma unroll
        for (int n2 = 0; n2 < 4; ++n2)
            bfr[n2] = *reinterpret_cast<const bf16x8*>((const char*)Bs + (wc + n2 * 16 + r) * 64 + g4 * 16);
#pragma unroll
        for (int m = 0; m < 4; ++m)
#pragma unroll
            for (int n2 = 0; n2 < 4; ++n2)
                acc[m][n2] = __builtin_amdgcn_mfma_f32_16x16x32_bf16(af[m], bfr[n2], acc[m][n2], 0, 0, 0);
        __syncthreads();
    }
#pragma unroll
    for (int n2 = 0; n2 < 4; ++n2) {
        int col = bn + wc + n2 * 16 + r;
        if (col >= ncols) continue;
        float bv = bias[col];
#pragma unroll
        for (int m = 0; m < 4; ++m) {
#pragma unroll
            for (int j = 0; j < 4; ++j) {
                int row = bm + wr + m * 16 + g4 * 4 + j;
                Yb[(size_t)row * ldy + col] = f2bf(acc[m][n2][j] + bv);
            }
        }
    }
}

// ---------- Epilogue: exp_map(+allzero), log, relu, exp_map, fused next log. bf16 in/out ----------
template <int NCP>
__global__ __launch_bounds__(64) void k_ep(const ushort_t* __restrict__ Y, int ldy,
                                           ushort_t* __restrict__ out, int ldo, int N) {
    constexpr int CH = NCP / 128;
    int i = blockIdx.x, t = threadIdx.x;
    const ushort_t* yr = Y + (size_t)i * ldy;
    float y[2 * CH];
#pragma unroll
    for (int c = 0; c < CH; ++c) {
        ushort2 v = *reinterpret_cast<const ushort2*>(yr + c * 128 + 2 * t);
        y[2 * c] = bf2f(v.x);
        y[2 * c + 1] = bf2f(v.y);
    }
    if (t == 63) y[2 * CH - 1] = 0.f;  // pad column
    float s1l = 0.f, sabl = 0.f;
#pragma unroll
    for (int q = 0; q < 2 * CH; ++q) { s1l += y[q] * y[q]; sabl += fabsf(y[q]); }
    float s1 = wredsum(s1l);
    float sab = wredsum(sabl);
    bool allz = (sab == 0.0f);
    float n = sqrtf(fmaxf(s1 + EPSF, 1e-6f));
    float sh = sinhf(fminf(n, 50.f));
    float fac = sh / n;
    float tq[2 * CH];
    float s2l = 0.f;
#pragma unroll
    for (int q = 0; q < 2 * CH; ++q) { tq[q] = allz ? 0.f : y[q] * fac; s2l += tq[q] * tq[q]; }
    float s2 = wredsum(s2l);
    float first = allz ? 0.f : sqrtf(1.f + s2);
    float dist = arcosh_f(first + EPSF);
    float rs = dist / sqrtf(s2 + EPSF);
    float rq[2 * CH];
    float s3l = 0.f;
#pragma unroll
    for (int q = 0; q < 2 * CH; ++q) { rq[q] = fmaxf(rs * tq[q], 0.f); s3l += rq[q] * rq[q]; }
    float s3 = wredsum(s3l);
    float n2 = sqrtf(fmaxf(s3 + EPSF, 1e-6f));
    float sh2 = sinhf(fminf(n2, 50.f));
    float fac2 = sh2 / n2;
    float uq[2 * CH];
    float s4l = 0.f;
#pragma unroll
    for (int q = 0; q < 2 * CH; ++q) { uq[q] = rq[q] * fac2; s4l += uq[q] * uq[q]; }
    float s4 = wredsum(s4l);
    float first2 = sqrtf(1.f + s4);
    float dist2 = arcosh_f(first2 + EPSF);
    float sc2 = dist2 / sqrtf(s4 + EPSF);
    ushort_t* orow = out + (size_t)i * ldo;
#pragma unroll
    for (int c = 0; c < CH; ++c) {
        ushort2 o;
        o.x = f2bf(sc2 * uq[2 * c]);
        o.y = f2bf(sc2 * uq[2 * c + 1]);
        *reinterpret_cast<ushort2*>(orow + c * 128 + 2 * t) = o;
    }
}

// ---------- mean partials: 2048 blocks x 192 thr, ushort2 loads (deterministic) ----------
__global__ __launch_bounds__(192) void k_mean(const char* __restrict__ Rbase,
                                              float* __restrict__ partials, int N, int chunk) {
    int b = blockIdx.x;
    int t = threadIdx.x;          // feature pair 2t, 2t+1
    int lo = b * chunk;
    int hi = lo + chunk; if (hi > N) hi = N;
    float a0 = 0.f, a1 = 0.f;
    const char* p = Rbase + (size_t)lo * 768 + 4 * t;
    for (int n = lo; n < hi; ++n, p += 768) {
        ushort2 v = *reinterpret_cast<const ushort2*>(p);
        a0 += bf2f(v.x);
        a1 += bf2f(v.y);
    }
    float* orow = partials + (size_t)b * 384;
    orow[2 * t] = a0;
    orow[2 * t + 1] = a1;
}

// ---------- stage-2 mean reduce: one block per feature, 2048 partials ----------
__global__ __launch_bounds__(256) void k_mred(const float* __restrict__ partials,
                                              float* __restrict__ hm, int nparts, int N) {
    __shared__ float sb[256];
    int j = blockIdx.x, t = threadIdx.x;
    float v = 0.f;
    for (int p = t; p < nparts; p += 256) v += partials[(size_t)p * 384 + j];
    sb[t] = v; __syncthreads();
    for (int st = 128; st > 0; st >>= 1) { if (t < st) sb[t] += sb[t + st]; __syncthreads(); }
    if (t == 0) hm[j] = sb[0] / (float)N;
}

// ---------- classifier head: single wave, parallel loads ----------
__global__ __launch_bounds__(64) void k_head(const float* __restrict__ hm,
                                             const float* __restrict__ Wc,
                                             const float* __restrict__ bc,
                                             float* __restrict__ dout, int ic, int oc) {
    int t = threadIdx.x;
    float h[6];
    float ss = 0.f;
#pragma unroll
    for (int c = 0; c < 6; ++c) {
        int j = t + 64 * c;
        h[c] = (j < ic) ? hm[j] : 0.f;
        ss += h[c] * h[c];
    }
    float ssum = wredsum(ss);
    float dist = arcosh_f(0.0f + EPSF);  // hm time component = 0
    float scl = dist / sqrtf(ssum + EPSF);
    float mxv[9];
#pragma unroll
    for (int o = 0; o < 9; ++o) {
        float p = 0.f;
        if (o < oc) {
#pragma unroll
            for (int c = 0; c < 6; ++c) {
                int j = t + 64 * c;
                if (j < ic) p += h[c] * Wc[(size_t)o * ic + j];
            }
        }
        float s = wredsum(p);
        mxv[o] = (o < oc) ? (scl * s + bc[o]) : 0.f;
    }
    if (t == 0) {
        float y[10], tt[10], lt[11], p[11], t3[11];
        float s1 = 0.f, sab = 0.f;
        for (int j = 0; j < 9; ++j) {
            y[j] = (j < oc) ? mxv[j] : 0.f;
            s1 += y[j] * y[j]; sab += fabsf(y[j]);
        }
        bool allz = (sab == 0.f);
        float n = sqrtf(fmaxf(s1 + EPSF, 1e-6f));
        float sh = sinhf(fminf(n, 50.f));
        float s2 = 0.f;
        for (int j = 0; j < oc; ++j) { tt[j] = allz ? 0.f : sh * y[j] / n; s2 += tt[j] * tt[j]; }
        float first = allz ? 0.f : sqrtf(1.f + s2);
        dout[0] = first;
        for (int j = 0; j < oc; ++j) dout[1 + j] = tt[j];
        float dist2 = arcosh_f(first + EPSF);
        float nrm2 = sqrtf(s2 + EPSF);
        lt[0] = 0.f;
        for (int j = 0; j < oc; ++j) lt[1 + j] = dist2 / nrm2 * tt[j];
        float m = lt[0];
        for (int j = 1; j <= oc; ++j) m = fmaxf(m, lt[j]);
        float es = 0.f;
        for (int j = 0; j <= oc; ++j) { p[j] = expf(lt[j] - m); es += p[j]; }
        for (int j = 0; j <= oc; ++j) p[j] /= es;
        p[0] = 0.f;
        float s3 = 0.f;
        for (int j = 1; j <= oc; ++j) s3 += p[j] * p[j];
        float n3 = sqrtf(fmaxf(s3 + EPSF, 1e-6f));
        float sh3 = sinhf(fminf(n3, 50.f));
        float s4 = 0.f;
        for (int j = 1; j <= oc; ++j) { t3[j] = sh3 * p[j] / n3; s4 += t3[j] * t3[j]; }
        dout[1 + oc] = sqrtf(1.f + s4);
        for (int j = 1; j <= oc; ++j) dout[1 + oc + j] = t3[j];
    }
}

extern "C" void kernel_launch(void* const* d_in, const int* in_sizes, int n_in,
                              void* d_out, int out_size, void* d_ws, size_t ws_size,
                              hipStream_t stream) {
    if (n_in < 10) return;
    const float* x   = (const float*)d_in[0];
    const int*   ei  = (const int*)d_in[1];
    const float* W0  = (const float*)d_in[2];
    const float* b0  = (const float*)d_in[3];
    const float* W1  = (const float*)d_in[4];
    const float* b1  = (const float*)d_in[5];
    const float* W2  = (const float*)d_in[6];
    const float* b2  = (const float*)d_in[7];
    const float* Wc  = (const float*)d_in[8];
    const float* bc  = (const float*)d_in[9];
    float* dout = (float*)d_out;

    int N = in_sizes[0] / 128;
    int E = in_sizes[1] / 2;
    int o1 = in_sizes[3];           // 127
    int i1 = in_sizes[2] / o1;      // 127
    int o2 = in_sizes[5];           // 255
    int i2 = in_sizes[4] / o2;      // 127
    int o3 = in_sizes[7];           // 383
    int i3 = in_sizes[6] / o3;      // 255
    int oc = in_sizes[9];           // 9
    int ic = in_sizes[8] / oc;      // 383

    int M_pad = ((N + 127) / 128) * 128;             // 50048
    int Kp1 = ((i1 + 31) / 32) * 32;                 // 128
    int Kp2 = ((i2 + 31) / 32) * 32;                 // 128
    int Kp3 = ((i3 + 31) / 32) * 32;                 // 256
    int Np1 = ((o1 + 127) / 128) * 128;              // 128
    int Np2 = ((o2 + 127) / 128) * 128;              // 256
    int Np3 = ((o3 + 127) / 128) * 128;              // 384

    const int* esrc = ei;
    const int* edst = ei + E;

    char* ws = (char*)d_ws;
    auto alloc = [&](size_t bytes) {
        char* p = ws;
        ws += (bytes + 511) & ~(size_t)511;
        return p;
    };
    ushort_t* Ab     = (ushort_t*)alloc((size_t)M_pad * 256 * 2);  // A (lo half) + xt0 (hi half)
    ushort_t* R      = (ushort_t*)alloc((size_t)M_pad * 384 * 2);  // Y / ht (bf16)
    ushort_t* Wb0    = (ushort_t*)alloc((size_t)Np1 * Kp1 * 2);
    ushort_t* Wb1    = (ushort_t*)alloc((size_t)Np2 * Kp2 * 2);
    ushort_t* Wb2    = (ushort_t*)alloc((size_t)Np3 * Kp3 * 2);
    int*      counts = (int*)alloc((size_t)N * 4);
    int*      row_ptr= (int*)alloc((size_t)(N + 1) * 4);
    int*      cursor = (int*)alloc((size_t)N * 4);
    int*      srcl   = (int*)alloc((size_t)E * 4);
    int*      bsum   = (int*)alloc(4096 * 4);
    int*      bscan  = (int*)alloc(4096 * 4);
    float*    partials = (float*)alloc((size_t)2048 * 384 * 4);
    float*    hmbuf  = (float*)alloc(512 * 4);
    (void)ws_size;

    int zb = (N + 255) / 256;
    int NB = (N + 1023) / 1024;
    int eb = (E + 255) / 256;

    int t1 = Np1 * Kp1, t2 = Np2 * Kp2, t3 = Np3 * Kp3;
    k_convw3<<<dim3((t1 + t2 + t3 + 255) / 256), dim3(256), 0, stream>>>(
        W0, W1, W2, Wb0, Wb1, Wb2, o1, i1, Kp1, o2, i2, Kp2, o3, i3, Kp3, t1, t2, t3);
    // 1. log_map_zero(x) -> xt0 bf16
    k_log0<<<dim3(N), dim3(64), 0, stream>>>(x, (char*)Ab, N);
    // 2. CSR build (one edge per thread)
    k_zero_i<<<dim3(zb), dim3(256), 0, stream>>>(counts, N);
    k_hist<<<dim3(eb), dim3(256), 0, stream>>>(edst, counts, E);
    k_bsum<<<dim3(NB), dim3(256), 0, stream>>>(counts, bsum, N);
    k_bscan<<<dim3(1), dim3(1), 0, stream>>>(bsum, bscan, row_ptr, NB, N);
    k_scan3<<<dim3(NB), dim3(256), 0, stream>>>(counts, bscan, row_ptr, cursor, N);
    k_fill<<<dim3(eb), dim3(256), 0, stream>>>(esrc, edst, cursor, srcl, E);
    // 3. aggregate (unrolled gather) + exp + fused log -> A (bf16)
    k_agg<<<dim3(N), dim3(64), 0, stream>>>((const char*)Ab, row_ptr, srcl, Ab, N);
    // 4. layer 1
    k_gemm<<<dim3(M_pad / 128, Np1 / 128), dim3(256), 0, stream>>>(Ab, 256, Wb0, Kp1, b0, R, 128, Kp1, o1);
    k_ep<128><<<dim3(N), dim3(64), 0, stream>>>(R, 128, Ab, 256, N);
    // 5. layer 2
    k_gemm<<<dim3(M_pad / 128, Np2 / 128), dim3(256), 0, stream>>>(Ab, 256, Wb1, Kp2, b1, R, 256, Kp2, o2);
    k_ep<256><<<dim3(N), dim3(64), 0, stream>>>(R, 256, Ab, 256, N);
    // 6. layer 3
    k_gemm<<<dim3(M_pad / 128, Np3 / 128), dim3(256), 0, stream>>>(Ab, 256, Wb2, Kp3, b2, R, 384, Kp3, o3);
    k_ep<384><<<dim3(N), dim3(64), 0, stream>>>(R, 384, R, 384, N);  // ht bf16 in-place
    // 7. deterministic mean: 2048-block stage 1 (ushort2 loads), per-feature stage 2
    int NBLK = 2048;
    int chunk = (N + NBLK - 1) / NBLK;
    k_mean<<<dim3(NBLK), dim3(192), 0, stream>>>((const char*)R, partials, N, chunk);
    k_mred<<<dim3(383), dim3(256), 0, stream>>>(partials, hmbuf, NBLK, N);
    // 8. classifier head (single wave, parallel loads)
    k_head<<<dim3(1), dim3(64), 0, stream>>>(hmbuf, Wc, bc, dout, ic, oc);
}